// Round 11
// baseline (307.128 us; speedup 1.0000x reference)
//
#include <hip/hip_runtime.h>
#include <math.h>

#define NIMG 16
#define A 3
#define HW 65536
#define AHW 196608
#define PRE 2000
#define POST 1000
#define CAP2 2048
#define MROWS 2048
#define NBUCKET 2048
#define NEGF (-1e30f)
#define LBUF 256
#define BW 0.01f
#define BD 4.0f
#define MBLK 64

__device__ __forceinline__ unsigned mapf(float x) {
    unsigned u = __float_as_uint(x);
    return (u & 0x80000000u) ? ~u : (u | 0x80000000u);
}

// threshold scan over a 2048-bucket histogram (256 threads), from the top.
// part[] is caller-provided shared scratch (256 entries).
__device__ __forceinline__ void thresh_scan(const unsigned* gh, unsigned* part,
                                            unsigned cum0, unsigned* outBucket,
                                            unsigned* outCumAbove) {
    int t = threadIdx.x;
    if (t < 256) {
        unsigned s = 0;
        for (int k = 0; k < 8; ++k) s += gh[t * 8 + k];
        part[t] = s;
    }
    __syncthreads();
    if (t == 0) {
        unsigned cum = cum0;
        int done = 0;
        for (int c = 255; c >= 0 && !done; --c) {
            if (cum + part[c] >= PRE) {
                for (int i = c * 8 + 7; i >= c * 8; --i) {
                    unsigned h = gh[i];
                    if (cum + h >= PRE) { *outBucket = (unsigned)i; *outCumAbove = cum; done = 1; break; }
                    cum += h;
                }
            } else {
                cum += part[c];
            }
        }
    }
}

// K1: per-image 11-bit histogram; LAST block per image also computes the
// coarse threshold bucket (fused k_thresh).
__global__ void __launch_bounds__(256) k_hist(const float4* __restrict__ obj4,
                                              unsigned* __restrict__ hist,
                                              unsigned* __restrict__ bsel,
                                              unsigned* __restrict__ cntAbove,
                                              unsigned* __restrict__ done1) {
    __shared__ unsigned lh[NBUCKET];
    __shared__ int isLast;
    int img = blockIdx.y;
    for (int i = threadIdx.x; i < NBUCKET; i += 256) lh[i] = 0;
    __syncthreads();
    const float4* p = obj4 + (size_t)img * (AHW / 4);
    int stride = gridDim.x * 256;
    for (int v = blockIdx.x * 256 + threadIdx.x; v < AHW / 4; v += stride) {
        float4 f = p[v];
        atomicAdd(&lh[mapf(f.x) >> 21], 1u);
        atomicAdd(&lh[mapf(f.y) >> 21], 1u);
        atomicAdd(&lh[mapf(f.z) >> 21], 1u);
        atomicAdd(&lh[mapf(f.w) >> 21], 1u);
    }
    __syncthreads();
    unsigned* gh = hist + img * NBUCKET;
    for (int i = threadIdx.x; i < NBUCKET; i += 256)
        if (lh[i]) atomicAdd(&gh[i], lh[i]);
    __threadfence();
    if (threadIdx.x == 0)
        isLast = (atomicAdd(&done1[img * 64], 1u) == gridDim.x - 1);
    __syncthreads();
    if (!isLast) return;
    __threadfence();
    unsigned bk, ca;
    thresh_scan(gh, lh, 0, &bk, &ca);
    if (threadIdx.x == 0) { bsel[img] = bk; cntAbove[img] = ca; }
}

// K2: 11-bit sub-histogram within coarse bucket B; LAST block per image also
// refines to the 22-bit threshold (fused k_thresh2).
__global__ void __launch_bounds__(256) k_hist2(const float4* __restrict__ obj4,
                                               const unsigned* __restrict__ bsel,
                                               const unsigned* __restrict__ cntAbove,
                                               unsigned* __restrict__ hist2,
                                               unsigned* __restrict__ thr32,
                                               unsigned* __restrict__ done2) {
    __shared__ unsigned lh[NBUCKET];
    __shared__ int isLast;
    int img = blockIdx.y;
    unsigned B = bsel[img];
    for (int i = threadIdx.x; i < NBUCKET; i += 256) lh[i] = 0;
    __syncthreads();
    const float4* p = obj4 + (size_t)img * (AHW / 4);
    int stride = gridDim.x * 256;
    for (int v = blockIdx.x * 256 + threadIdx.x; v < AHW / 4; v += stride) {
        float4 f = p[v];
        unsigned m0 = mapf(f.x), m1 = mapf(f.y), m2 = mapf(f.z), m3 = mapf(f.w);
        if ((m0 >> 21) == B) atomicAdd(&lh[(m0 >> 10) & 0x7FF], 1u);
        if ((m1 >> 21) == B) atomicAdd(&lh[(m1 >> 10) & 0x7FF], 1u);
        if ((m2 >> 21) == B) atomicAdd(&lh[(m2 >> 10) & 0x7FF], 1u);
        if ((m3 >> 21) == B) atomicAdd(&lh[(m3 >> 10) & 0x7FF], 1u);
    }
    __syncthreads();
    unsigned* gh = hist2 + img * NBUCKET;
    for (int i = threadIdx.x; i < NBUCKET; i += 256)
        if (lh[i]) atomicAdd(&gh[i], lh[i]);
    __threadfence();
    if (threadIdx.x == 0)
        isLast = (atomicAdd(&done2[img * 64], 1u) == gridDim.x - 1);
    __syncthreads();
    if (!isLast) return;
    __threadfence();
    unsigned bk, ca;
    thresh_scan(gh, lh, cntAbove[img], &bk, &ca);
    if (threadIdx.x == 0) thr32[img] = (B << 21) | (bk << 10);
}

// K3: compact candidates with m >= thr. Two-level: LDS staging + one global
// atomic per block (selcnt padded to a private cache line per image).
__global__ void __launch_bounds__(256) k_compact(const float4* __restrict__ obj4,
                                                 const unsigned* __restrict__ thr32,
                                                 unsigned* __restrict__ selcnt,
                                                 unsigned long long* __restrict__ keys) {
    __shared__ unsigned long long lbuf[LBUF];
    __shared__ unsigned lcnt, gbase;
    int img = blockIdx.y;
    unsigned thr = thr32[img];
    if (threadIdx.x == 0) lcnt = 0;
    __syncthreads();
    const float4* p = obj4 + (size_t)img * (AHW / 4);
    int v0 = blockIdx.x * 768;
    #pragma unroll
    for (int it = 0; it < 3; ++it) {
        int v = v0 + it * 256 + threadIdx.x;
        float4 f = p[v];
        int jb = v * 4;
        #pragma unroll
        for (int k = 0; k < 4; ++k) {
            float x = k == 0 ? f.x : (k == 1 ? f.y : (k == 2 ? f.z : f.w));
            unsigned m = mapf(x);
            if (m >= thr) {
                int j = jb + k;
                int a = j >> 16;
                int hw = j & 65535;
                unsigned idx = (unsigned)(hw * A + a);
                unsigned pos = atomicAdd(&lcnt, 1u);
                if (pos < LBUF)
                    lbuf[pos] = ((unsigned long long)m << 32) | (unsigned)(~idx);
            }
        }
    }
    __syncthreads();
    unsigned n = lcnt > LBUF ? LBUF : lcnt;
    if (threadIdx.x == 0) gbase = atomicAdd(&selcnt[img * 64], n);
    __syncthreads();
    if (threadIdx.x < n) {
        unsigned pos = gbase + threadIdx.x;
        if (pos < CAP2)
            keys[(size_t)img * CAP2 + pos] = lbuf[threadIdx.x];
    }
}

// K4: per-image bitonic sort (descending, LDS) FUSED with box decode.
// Keys never return to global: after the sort, the same block decodes the
// top PRE candidates straight from LDS (f64 exact path + f32 screen copy).
__global__ void __launch_bounds__(512) k_sortdec(unsigned long long* __restrict__ keys,
                                                 const unsigned* __restrict__ selcnt,
                                                 const float* __restrict__ anchors,
                                                 const float* __restrict__ br,
                                                 double* __restrict__ boxes,
                                                 float4* __restrict__ boxesf,
                                                 float* __restrict__ scores,
                                                 unsigned* __restrict__ negmask) {
    __shared__ unsigned long long s[CAP2];
    int img = blockIdx.x;
    unsigned cnt = selcnt[img * 64];
    if (cnt > CAP2) cnt = CAP2;
    unsigned long long* g = keys + (size_t)img * CAP2;
    for (int i = threadIdx.x; i < CAP2; i += 512)
        s[i] = (i < (int)cnt) ? g[i] : 0ULL;
    __syncthreads();
    for (int k2 = 2; k2 <= CAP2; k2 <<= 1) {
        for (int j = k2 >> 1; j > 0; j >>= 1) {
            for (int i = threadIdx.x; i < CAP2; i += 512) {
                int ixj = i ^ j;
                if (ixj > i) {
                    unsigned long long a = s[i], b = s[ixj];
                    bool up = ((i & k2) == 0);
                    if (up ? (a < b) : (a > b)) { s[i] = b; s[ixj] = a; }
                }
            }
            __syncthreads();
        }
    }
    // ---- decode phase (was k_decode) ----
    for (int r = threadIdx.x; r < PRE; r += 512) {
        unsigned long long key = s[r];
        unsigned m = (unsigned)(key >> 32);
        unsigned idx = ~(unsigned)key;
        unsigned u = (m & 0x80000000u) ? (m ^ 0x80000000u) : ~m;
        float x = __uint_as_float(u);
        double sc = 1.0 / (1.0 + exp(-(double)x));
        int a = idx % 3;
        int hw = idx / 3;
        const float* anc = anchors + ((size_t)img * AHW + idx) * 4;
        double ax1 = anc[0], ay1 = anc[1], ax2 = anc[2], ay2 = anc[3];
        double aw = ax2 - ax1 + 1.0, ah = ay2 - ay1 + 1.0;
        double cx = ax1 + 0.5 * aw, cy = ay1 + 0.5 * ah;
        const float* bp = br + (size_t)img * 12 * HW + (size_t)a * 4 * HW + hw;
        double dx = bp[0];
        double dy = bp[(size_t)HW];
        double dw = bp[(size_t)2 * HW];
        double dh = bp[(size_t)3 * HW];
        const double CLIPV = 4.135166556742356; // log(1000/16)
        dw = fmin(dw, CLIPV); dh = fmin(dh, CLIPV);
        double pcx = dx * aw + cx, pcy = dy * ah + cy;
        double pw = exp(dw) * aw, ph = exp(dh) * ah;
        double x1 = pcx - 0.5 * pw, y1 = pcy - 0.5 * ph;
        double x2 = pcx + 0.5 * pw - 1.0, y2 = pcy + 0.5 * ph - 1.0;
        x1 = fmin(fmax(x1, 0.0), 1023.0);
        y1 = fmin(fmax(y1, 0.0), 1023.0);
        x2 = fmin(fmax(x2, 0.0), 1023.0);
        y2 = fmin(fmax(y2, 0.0), 1023.0);
        bool keep = (x2 - x1 + 1.0 >= 0.0) && (y2 - y1 + 1.0 >= 0.0);
        double* bo = boxes + ((size_t)img * PRE + r) * 4;
        bo[0] = x1; bo[1] = y1; bo[2] = x2; bo[3] = y2;
        float4 bf;
        bf.x = (float)x1; bf.y = (float)y1; bf.z = (float)x2; bf.w = (float)y2;
        boxesf[(size_t)img * PRE + r] = bf;
        scores[img * PRE + r] = keep ? (float)sc : NEGF;
        if (!keep) atomicOr(&negmask[img * 64 + (r >> 5)], 1u << (r & 31));
    }
}

// K5: upper-triangle IoU suppression bitmask. BRANCH-FREE f32 screen inner
// loop (predication only); rare rows with borderline pairs are rebuilt in a
// per-row exact fixup pass (f64, reference formula). LDS: float4 box + 0.7*area,
// padded to 2048 with sentinels. Strided rows for balance; 40960B -> 4 blk/CU.
__global__ void __launch_bounds__(256) k_mask(const float4* __restrict__ boxesf,
                                              const double* __restrict__ boxes,
                                              unsigned* __restrict__ mask) {
    __shared__ float4 sb[MROWS];
    __shared__ float sa7[MROWS];
    int img = blockIdx.y;
    int tid = threadIdx.x;
    int wave = tid >> 6, t = tid & 63;
    const float4* fb = boxesf + (size_t)img * PRE;
    for (int i = tid; i < MROWS; i += 256) {
        float4 b;
        if (i < PRE) {
            b = fb[i];
        } else {
            b.x = 1e8f; b.y = 1e8f; b.z = -1e8f; b.w = -1e8f;  // sentinel: never overlaps
        }
        sb[i] = b;
        sa7[i] = 0.7f * ((b.z - b.x + 1.0f) * (b.w - b.y + 1.0f));
    }
    __syncthreads();
    const double* base64 = boxes + (size_t)img * PRE * 4;
    for (int rr = 0; rr < 8; ++rr) {
        int r = blockIdx.x + MBLK * (rr * 4 + wave);   // strided row map
        if (r >= PRE) break;
        float4 p = sb[r];
        float a7r = sa7[r];
        int kmin = r >> 6;
        unsigned myw = 0;
        bool anyneed = false;
        for (int k = kmin; k < 32; ++k) {
            int col = 64 * k + t;
            float4 q = sb[col];
            float iw = fminf(p.z, q.z) - fmaxf(p.x, q.x) + 1.0f;
            float ih = fminf(p.w, q.w) - fmaxf(p.y, q.y) + 1.0f;
            float inter = iw * ih;
            float d = fmaf(1.7f, inter, -(a7r + sa7[col]));
            bool ov = (iw > -BW) & (ih > -BW);
            bool need = ov & ((iw < BW) | (ih < BW) | (fabsf(d) < BD));
            bool res = ov & (d > 0.0f);
            anyneed |= need;
            unsigned long long bb = __ballot(res);
            myw = (t == 2 * k) ? (unsigned)bb : myw;
            myw = (t == 2 * k + 1) ? (unsigned)(bb >> 32) : myw;
        }
        if (__any(anyneed)) {
            // rare: rebuild row exactly, resolving borderline pairs in f64
            const double* ri = base64 + (size_t)r * 4;
            double X1 = ri[0], Y1 = ri[1], X2 = ri[2], Y2 = ri[3];
            double AR = (X2 - X1 + 1.0) * (Y2 - Y1 + 1.0);
            myw = 0;
            for (int k = kmin; k < 32; ++k) {
                int col = 64 * k + t;
                float4 q = sb[col];
                float iw = fminf(p.z, q.z) - fmaxf(p.x, q.x) + 1.0f;
                float ih = fminf(p.w, q.w) - fmaxf(p.y, q.y) + 1.0f;
                float inter = iw * ih;
                float d = fmaf(1.7f, inter, -(a7r + sa7[col]));
                bool ov = (iw > -BW) & (ih > -BW);
                bool need = ov & ((iw < BW) | (ih < BW) | (fabsf(d) < BD));
                bool res = ov & (d > 0.0f);
                if (need) {   // col < PRE guaranteed (sentinels can't set need)
                    const double* rj = base64 + (size_t)col * 4;
                    double bX1 = rj[0], bY1 = rj[1], bX2 = rj[2], bY2 = rj[3];
                    double IW = fmin(X2, bX2) - fmax(X1, bX1) + 1.0;
                    double IH = fmin(Y2, bY2) - fmax(Y1, bY1) + 1.0;
                    IW = IW > 0.0 ? IW : 0.0;
                    IH = IH > 0.0 ? IH : 0.0;
                    double INTER = IW * IH;
                    double AJ = (bX2 - bX1 + 1.0) * (bY2 - bY1 + 1.0);
                    double IOU = INTER / ((AR + AJ) - INTER);
                    res = IOU > 0.7;
                }
                unsigned long long bb = __ballot(res);
                myw = (t == 2 * k) ? (unsigned)bb : myw;
                myw = (t == 2 * k + 1) ? (unsigned)(bb >> 32) : myw;
            }
        }
        mask[((size_t)img * MROWS + r) * 64 + t] = myw;
    }
}

// K6: sequential-scan greedy NMS, branchless scalar-mirror inner loop.
#define NMS_LOAD(B, G)                                          \
    _Pragma("unroll")                                           \
    for (int s = 0; s < 16; ++s) B[s] = mrow[((G) * 16 + s) * 64];

#define NMS_PROC(B, G, PAR) {                                   \
    int W = (G) >> 1;                                           \
    if ((PAR) == 0) s_cur = (unsigned)__builtin_amdgcn_readlane((int)sup, W); \
    _Pragma("unroll")                                           \
    for (int s = 0; s < 16; ++s) {                              \
        unsigned rb = (unsigned)__builtin_amdgcn_readlane((int)B[s], W); \
        unsigned bit = (s_cur >> (((PAR) << 4) + s)) & 1u;      \
        unsigned am = bit - 1u;  /* alive: ~0, dead: 0 */       \
        s_cur |= rb & am;                                       \
        s_pick |= am & (1u << (((PAR) << 4) + s));              \
        sup |= B[s] & am;                                       \
    }                                                           \
    if ((PAR) == 1) {                                           \
        pickedv = (t == W) ? (int)s_pick : pickedv;             \
        np += __builtin_popcount(s_pick);                       \
        s_pick = 0;                                             \
    }                                                           \
}

__global__ void __launch_bounds__(64) k_nms(const double* __restrict__ boxes,
                                            const float* __restrict__ scores,
                                            const unsigned* __restrict__ negmask,
                                            const unsigned* __restrict__ mask,
                                            float* __restrict__ out) {
    __shared__ int picks[POST];
    __shared__ unsigned wcnt[64];
    __shared__ int tot;
    int img = blockIdx.x;
    int t = threadIdx.x;
    unsigned sup = negmask[img * 64 + t];
    if (t == 62) sup |= 0xFFFF0000u;  // indices 2000..2015 invalid
    if (t == 63) sup = 0xFFFFFFFFu;   // indices 2016..2047 invalid
    const unsigned* mrow = mask + (size_t)img * MROWS * 64 + t;
    unsigned b0[16], b1[16], b2[16], b3[16];
    NMS_LOAD(b0, 0)
    NMS_LOAD(b1, 1)
    NMS_LOAD(b2, 2)
    NMS_LOAD(b3, 3)
    int np = 0;
    unsigned s_cur = 0, s_pick = 0;
    int pickedv = 0;
    // 125 groups of 16 rows (2000). Main loop: groups 0..123; epilogue: 124.
    for (int gg = 0; gg < 124; gg += 4) {
        NMS_PROC(b0, gg + 0, 0) NMS_LOAD(b0, gg + 4)
        NMS_PROC(b1, gg + 1, 1) NMS_LOAD(b1, gg + 5)
        NMS_PROC(b2, gg + 2, 0) NMS_LOAD(b2, gg + 6)
        NMS_PROC(b3, gg + 3, 1) NMS_LOAD(b3, gg + 7)   // max load group 127 < MROWS/16
        if (np >= POST) break;
    }
    if (np < POST) {
        NMS_PROC(b0, 124, 0)   // jj 1984..1999, word 62 low half
        pickedv = (t == 62) ? (int)s_pick : pickedv;
        np += __builtin_popcount(s_pick);
    }
    // epilogue: materialize picks[] from the bitmap (lane W holds word W)
    wcnt[t] = (unsigned)__builtin_popcount((unsigned)pickedv);
    __syncthreads();
    int pre = 0;
    for (int i = 0; i < t; ++i) pre += (int)wcnt[i];
    if (t == 63) tot = pre + (int)wcnt[63];
    __syncthreads();
    unsigned pw = (unsigned)pickedv;
    int rank = pre;
    while (pw) {
        int b = __ffs(pw) - 1;
        pw &= pw - 1;
        if (rank < POST) picks[rank] = t * 32 + b;
        rank++;
    }
    __syncthreads();
    int np_final = tot > POST ? POST : tot;
    float* ob = out + (size_t)img * POST * 4;
    float* os = out + (size_t)NIMG * POST * 4 + (size_t)img * POST;
    for (int k = t; k < POST; k += 64) {
        if (k < np_final) {
            int p = picks[k];
            const double* bp = boxes + ((size_t)img * PRE + p) * 4;
            ob[k * 4 + 0] = (float)bp[0];
            ob[k * 4 + 1] = (float)bp[1];
            ob[k * 4 + 2] = (float)bp[2];
            ob[k * 4 + 3] = (float)bp[3];
            os[k] = scores[img * PRE + p];
        } else {
            ob[k * 4 + 0] = 0.0f; ob[k * 4 + 1] = 0.0f;
            ob[k * 4 + 2] = 0.0f; ob[k * 4 + 3] = 0.0f;
            os[k] = NEGF;
        }
    }
}

extern "C" void kernel_launch(void* const* d_in, const int* in_sizes, int n_in,
                              void* d_out, int out_size, void* d_ws, size_t ws_size,
                              hipStream_t stream) {
    const float* anchors = (const float*)d_in[0];
    const float4* obj4 = (const float4*)d_in[1];
    const float* br = (const float*)d_in[2];
    float* out = (float*)d_out;

    char* ws = (char*)d_ws;
    size_t off = 0;
    auto alloc = [&](size_t bytes) {
        void* p = ws + off;
        off = (off + bytes + 255) & ~(size_t)255;
        return p;
    };
    // zero-initialized region (single fused memset)
    unsigned* hist = (unsigned*)alloc((size_t)NIMG * NBUCKET * 4);
    unsigned* hist2 = (unsigned*)alloc((size_t)NIMG * NBUCKET * 4);
    unsigned* done1 = (unsigned*)alloc((size_t)NIMG * 64 * 4);
    unsigned* done2 = (unsigned*)alloc((size_t)NIMG * 64 * 4);
    unsigned* selcnt = (unsigned*)alloc((size_t)NIMG * 64 * 4);      // one cache line per image
    unsigned* negmask = (unsigned*)alloc((size_t)NIMG * 64 * 4);
    size_t zero_bytes = off;
    // non-zeroed buffers
    unsigned* bsel = (unsigned*)alloc(NIMG * 4);
    unsigned* cntAbove = (unsigned*)alloc(NIMG * 4);
    unsigned* thr32 = (unsigned*)alloc(NIMG * 4);
    unsigned long long* keys = (unsigned long long*)alloc((size_t)NIMG * CAP2 * 8);
    double* boxes = (double*)alloc((size_t)NIMG * PRE * 4 * 8);
    float4* boxesf = (float4*)alloc((size_t)NIMG * PRE * 16);
    float* scores = (float*)alloc((size_t)NIMG * PRE * 4);
    unsigned* mask = (unsigned*)alloc((size_t)NIMG * MROWS * 64 * 4);

    hipMemsetAsync(hist, 0, zero_bytes, stream);

    k_hist<<<dim3(64, NIMG), 256, 0, stream>>>(obj4, hist, bsel, cntAbove, done1);
    k_hist2<<<dim3(64, NIMG), 256, 0, stream>>>(obj4, bsel, cntAbove, hist2, thr32, done2);
    k_compact<<<dim3(64, NIMG), 256, 0, stream>>>(obj4, thr32, selcnt, keys);
    k_sortdec<<<NIMG, 512, 0, stream>>>(keys, selcnt, anchors, br, boxes, boxesf, scores, negmask);
    k_mask<<<dim3(MBLK, NIMG), 256, 0, stream>>>(boxesf, boxes, mask);
    k_nms<<<NIMG, 64, 0, stream>>>(boxes, scores, negmask, mask, out);
}

// Round 12
// 284.130 us; speedup vs baseline: 1.0809x; 1.0809x over previous
//
#include <hip/hip_runtime.h>
#include <math.h>

#define NIMG 16
#define A 3
#define HW 65536
#define AHW 196608
#define PRE 2000
#define POST 1000
#define CAP2 2048
#define MROWS 2048
#define NBUCKET 2048
#define NEGF (-1e30f)
#define LBUF 256
#define BW 0.01f
#define BD 4.0f
#define MBLK 64

__device__ __forceinline__ unsigned mapf(float x) {
    unsigned u = __float_as_uint(x);
    return (u & 0x80000000u) ? ~u : (u | 0x80000000u);
}

// threshold scan over a 2048-bucket histogram (256 threads), from the top.
// part[] is caller-provided shared scratch (256 entries).
__device__ __forceinline__ void thresh_scan(const unsigned* gh, unsigned* part,
                                            unsigned cum0, unsigned* outBucket,
                                            unsigned* outCumAbove) {
    int t = threadIdx.x;
    if (t < 256) {
        unsigned s = 0;
        for (int k = 0; k < 8; ++k) s += gh[t * 8 + k];
        part[t] = s;
    }
    __syncthreads();
    if (t == 0) {
        unsigned cum = cum0;
        int done = 0;
        for (int c = 255; c >= 0 && !done; --c) {
            if (cum + part[c] >= PRE) {
                for (int i = c * 8 + 7; i >= c * 8; --i) {
                    unsigned h = gh[i];
                    if (cum + h >= PRE) { *outBucket = (unsigned)i; *outCumAbove = cum; done = 1; break; }
                    cum += h;
                }
            } else {
                cum += part[c];
            }
        }
    }
}

// K1: per-image 11-bit histogram; LAST block per image also computes the
// coarse threshold bucket (fused k_thresh).
__global__ void __launch_bounds__(256) k_hist(const float4* __restrict__ obj4,
                                              unsigned* __restrict__ hist,
                                              unsigned* __restrict__ bsel,
                                              unsigned* __restrict__ cntAbove,
                                              unsigned* __restrict__ done1) {
    __shared__ unsigned lh[NBUCKET];
    __shared__ int isLast;
    int img = blockIdx.y;
    for (int i = threadIdx.x; i < NBUCKET; i += 256) lh[i] = 0;
    __syncthreads();
    const float4* p = obj4 + (size_t)img * (AHW / 4);
    int stride = gridDim.x * 256;
    for (int v = blockIdx.x * 256 + threadIdx.x; v < AHW / 4; v += stride) {
        float4 f = p[v];
        atomicAdd(&lh[mapf(f.x) >> 21], 1u);
        atomicAdd(&lh[mapf(f.y) >> 21], 1u);
        atomicAdd(&lh[mapf(f.z) >> 21], 1u);
        atomicAdd(&lh[mapf(f.w) >> 21], 1u);
    }
    __syncthreads();
    unsigned* gh = hist + img * NBUCKET;
    for (int i = threadIdx.x; i < NBUCKET; i += 256)
        if (lh[i]) atomicAdd(&gh[i], lh[i]);
    __threadfence();
    if (threadIdx.x == 0)
        isLast = (atomicAdd(&done1[img * 64], 1u) == gridDim.x - 1);
    __syncthreads();
    if (!isLast) return;
    __threadfence();
    unsigned bk, ca;
    thresh_scan(gh, lh, 0, &bk, &ca);
    if (threadIdx.x == 0) { bsel[img] = bk; cntAbove[img] = ca; }
}

// K2: 11-bit sub-histogram within coarse bucket B; LAST block per image also
// refines to the 22-bit threshold (fused k_thresh2).
__global__ void __launch_bounds__(256) k_hist2(const float4* __restrict__ obj4,
                                               const unsigned* __restrict__ bsel,
                                               const unsigned* __restrict__ cntAbove,
                                               unsigned* __restrict__ hist2,
                                               unsigned* __restrict__ thr32,
                                               unsigned* __restrict__ done2) {
    __shared__ unsigned lh[NBUCKET];
    __shared__ int isLast;
    int img = blockIdx.y;
    unsigned B = bsel[img];
    for (int i = threadIdx.x; i < NBUCKET; i += 256) lh[i] = 0;
    __syncthreads();
    const float4* p = obj4 + (size_t)img * (AHW / 4);
    int stride = gridDim.x * 256;
    for (int v = blockIdx.x * 256 + threadIdx.x; v < AHW / 4; v += stride) {
        float4 f = p[v];
        unsigned m0 = mapf(f.x), m1 = mapf(f.y), m2 = mapf(f.z), m3 = mapf(f.w);
        if ((m0 >> 21) == B) atomicAdd(&lh[(m0 >> 10) & 0x7FF], 1u);
        if ((m1 >> 21) == B) atomicAdd(&lh[(m1 >> 10) & 0x7FF], 1u);
        if ((m2 >> 21) == B) atomicAdd(&lh[(m2 >> 10) & 0x7FF], 1u);
        if ((m3 >> 21) == B) atomicAdd(&lh[(m3 >> 10) & 0x7FF], 1u);
    }
    __syncthreads();
    unsigned* gh = hist2 + img * NBUCKET;
    for (int i = threadIdx.x; i < NBUCKET; i += 256)
        if (lh[i]) atomicAdd(&gh[i], lh[i]);
    __threadfence();
    if (threadIdx.x == 0)
        isLast = (atomicAdd(&done2[img * 64], 1u) == gridDim.x - 1);
    __syncthreads();
    if (!isLast) return;
    __threadfence();
    unsigned bk, ca;
    thresh_scan(gh, lh, cntAbove[img], &bk, &ca);
    if (threadIdx.x == 0) thr32[img] = (B << 21) | (bk << 10);
}

// K3: compact candidates with m >= thr. Two-level: LDS staging + one global
// atomic per block (selcnt padded to a private cache line per image).
__global__ void __launch_bounds__(256) k_compact(const float4* __restrict__ obj4,
                                                 const unsigned* __restrict__ thr32,
                                                 unsigned* __restrict__ selcnt,
                                                 unsigned long long* __restrict__ keys) {
    __shared__ unsigned long long lbuf[LBUF];
    __shared__ unsigned lcnt, gbase;
    int img = blockIdx.y;
    unsigned thr = thr32[img];
    if (threadIdx.x == 0) lcnt = 0;
    __syncthreads();
    const float4* p = obj4 + (size_t)img * (AHW / 4);
    int v0 = blockIdx.x * 768;
    #pragma unroll
    for (int it = 0; it < 3; ++it) {
        int v = v0 + it * 256 + threadIdx.x;
        float4 f = p[v];
        int jb = v * 4;
        #pragma unroll
        for (int k = 0; k < 4; ++k) {
            float x = k == 0 ? f.x : (k == 1 ? f.y : (k == 2 ? f.z : f.w));
            unsigned m = mapf(x);
            if (m >= thr) {
                int j = jb + k;
                int a = j >> 16;
                int hw = j & 65535;
                unsigned idx = (unsigned)(hw * A + a);
                unsigned pos = atomicAdd(&lcnt, 1u);
                if (pos < LBUF)
                    lbuf[pos] = ((unsigned long long)m << 32) | (unsigned)(~idx);
            }
        }
    }
    __syncthreads();
    unsigned n = lcnt > LBUF ? LBUF : lcnt;
    if (threadIdx.x == 0) gbase = atomicAdd(&selcnt[img * 64], n);
    __syncthreads();
    if (threadIdx.x < n) {
        unsigned pos = gbase + threadIdx.x;
        if (pos < CAP2)
            keys[(size_t)img * CAP2 + pos] = lbuf[threadIdx.x];
    }
}

// K4: per-image bitonic sort, descending (1024 threads). Tail beyond the
// valid count padded with 0 keys in LDS.
__global__ void __launch_bounds__(1024) k_sort(unsigned long long* __restrict__ keys,
                                               const unsigned* __restrict__ selcnt) {
    __shared__ unsigned long long s[CAP2];
    int img = blockIdx.x;
    unsigned cnt = selcnt[img * 64];
    if (cnt > CAP2) cnt = CAP2;
    unsigned long long* g = keys + (size_t)img * CAP2;
    for (int i = threadIdx.x; i < CAP2; i += 1024)
        s[i] = (i < (int)cnt) ? g[i] : 0ULL;
    __syncthreads();
    for (int k2 = 2; k2 <= CAP2; k2 <<= 1) {
        for (int j = k2 >> 1; j > 0; j >>= 1) {
            for (int i = threadIdx.x; i < CAP2; i += 1024) {
                int ixj = i ^ j;
                if (ixj > i) {
                    unsigned long long a = s[i], b = s[ixj];
                    bool up = ((i & k2) == 0);
                    if (up ? (a < b) : (a > b)) { s[i] = b; s[ixj] = a; }
                }
            }
            __syncthreads();
        }
    }
    for (int i = threadIdx.x; i < PRE; i += 1024) g[i] = s[i];
}

// K5: decode boxes (f64), clip, MIN_SIZE filter, sigmoid score.
// Writes f64 boxes (exact path) AND f32 boxes (screen path). 125 blocks.
__global__ void k_decode(const float* __restrict__ anchors, const float* __restrict__ br,
                         const unsigned long long* __restrict__ keys,
                         double* __restrict__ boxes, float4* __restrict__ boxesf,
                         float* __restrict__ scores, unsigned* __restrict__ negmask) {
    int g = blockIdx.x * blockDim.x + threadIdx.x;
    if (g >= NIMG * PRE) return;
    int img = g / PRE, r = g % PRE;
    unsigned long long key = keys[(size_t)img * CAP2 + r];
    unsigned m = (unsigned)(key >> 32);
    unsigned idx = ~(unsigned)key;
    unsigned u = (m & 0x80000000u) ? (m ^ 0x80000000u) : ~m;
    float x = __uint_as_float(u);
    double sc = 1.0 / (1.0 + exp(-(double)x));
    int a = idx % 3;
    int hw = idx / 3;
    const float* anc = anchors + ((size_t)img * AHW + idx) * 4;
    double ax1 = anc[0], ay1 = anc[1], ax2 = anc[2], ay2 = anc[3];
    double aw = ax2 - ax1 + 1.0, ah = ay2 - ay1 + 1.0;
    double cx = ax1 + 0.5 * aw, cy = ay1 + 0.5 * ah;
    const float* bp = br + (size_t)img * 12 * HW + (size_t)a * 4 * HW + hw;
    double dx = bp[0];
    double dy = bp[(size_t)HW];
    double dw = bp[(size_t)2 * HW];
    double dh = bp[(size_t)3 * HW];
    const double CLIPV = 4.135166556742356; // log(1000/16)
    dw = fmin(dw, CLIPV); dh = fmin(dh, CLIPV);
    double pcx = dx * aw + cx, pcy = dy * ah + cy;
    double pw = exp(dw) * aw, ph = exp(dh) * ah;
    double x1 = pcx - 0.5 * pw, y1 = pcy - 0.5 * ph;
    double x2 = pcx + 0.5 * pw - 1.0, y2 = pcy + 0.5 * ph - 1.0;
    x1 = fmin(fmax(x1, 0.0), 1023.0);
    y1 = fmin(fmax(y1, 0.0), 1023.0);
    x2 = fmin(fmax(x2, 0.0), 1023.0);
    y2 = fmin(fmax(y2, 0.0), 1023.0);
    bool keep = (x2 - x1 + 1.0 >= 0.0) && (y2 - y1 + 1.0 >= 0.0);
    double* bo = boxes + ((size_t)img * PRE + r) * 4;
    bo[0] = x1; bo[1] = y1; bo[2] = x2; bo[3] = y2;
    float4 bf;
    bf.x = (float)x1; bf.y = (float)y1; bf.z = (float)x2; bf.w = (float)y2;
    boxesf[(size_t)img * PRE + r] = bf;
    scores[img * PRE + r] = keep ? (float)sc : NEGF;
    if (!keep) atomicOr(&negmask[img * 64 + (r >> 5)], 1u << (r & 31));
}

// K6: upper-triangle IoU suppression bitmask. BRANCH-FREE f32 screen inner
// loop (predication only); rare rows with borderline pairs are rebuilt in a
// per-row exact fixup pass (f64, reference formula). LDS: float4 box + 0.7*area,
// padded to 2048 with sentinels. Strided rows for balance; 40960B -> 4 blk/CU.
__global__ void __launch_bounds__(256) k_mask(const float4* __restrict__ boxesf,
                                              const double* __restrict__ boxes,
                                              unsigned* __restrict__ mask) {
    __shared__ float4 sb[MROWS];
    __shared__ float sa7[MROWS];
    int img = blockIdx.y;
    int tid = threadIdx.x;
    int wave = tid >> 6, t = tid & 63;
    const float4* fb = boxesf + (size_t)img * PRE;
    for (int i = tid; i < MROWS; i += 256) {
        float4 b;
        if (i < PRE) {
            b = fb[i];
        } else {
            b.x = 1e8f; b.y = 1e8f; b.z = -1e8f; b.w = -1e8f;  // sentinel: never overlaps
        }
        sb[i] = b;
        sa7[i] = 0.7f * ((b.z - b.x + 1.0f) * (b.w - b.y + 1.0f));
    }
    __syncthreads();
    const double* base64 = boxes + (size_t)img * PRE * 4;
    for (int rr = 0; rr < 8; ++rr) {
        int r = blockIdx.x + MBLK * (rr * 4 + wave);   // strided row map
        if (r >= PRE) break;
        float4 p = sb[r];
        float a7r = sa7[r];
        int kmin = r >> 6;
        unsigned myw = 0;
        bool anyneed = false;
        for (int k = kmin; k < 32; ++k) {
            int col = 64 * k + t;
            float4 q = sb[col];
            float iw = fminf(p.z, q.z) - fmaxf(p.x, q.x) + 1.0f;
            float ih = fminf(p.w, q.w) - fmaxf(p.y, q.y) + 1.0f;
            float inter = iw * ih;
            float d = fmaf(1.7f, inter, -(a7r + sa7[col]));
            bool ov = (iw > -BW) & (ih > -BW);
            bool need = ov & ((iw < BW) | (ih < BW) | (fabsf(d) < BD));
            bool res = ov & (d > 0.0f);
            anyneed |= need;
            unsigned long long bb = __ballot(res);
            myw = (t == 2 * k) ? (unsigned)bb : myw;
            myw = (t == 2 * k + 1) ? (unsigned)(bb >> 32) : myw;
        }
        if (__any(anyneed)) {
            // rare: rebuild row exactly, resolving borderline pairs in f64
            const double* ri = base64 + (size_t)r * 4;
            double X1 = ri[0], Y1 = ri[1], X2 = ri[2], Y2 = ri[3];
            double AR = (X2 - X1 + 1.0) * (Y2 - Y1 + 1.0);
            myw = 0;
            for (int k = kmin; k < 32; ++k) {
                int col = 64 * k + t;
                float4 q = sb[col];
                float iw = fminf(p.z, q.z) - fmaxf(p.x, q.x) + 1.0f;
                float ih = fminf(p.w, q.w) - fmaxf(p.y, q.y) + 1.0f;
                float inter = iw * ih;
                float d = fmaf(1.7f, inter, -(a7r + sa7[col]));
                bool ov = (iw > -BW) & (ih > -BW);
                bool need = ov & ((iw < BW) | (ih < BW) | (fabsf(d) < BD));
                bool res = ov & (d > 0.0f);
                if (need) {   // col < PRE guaranteed (sentinels can't set need)
                    const double* rj = base64 + (size_t)col * 4;
                    double bX1 = rj[0], bY1 = rj[1], bX2 = rj[2], bY2 = rj[3];
                    double IW = fmin(X2, bX2) - fmax(X1, bX1) + 1.0;
                    double IH = fmin(Y2, bY2) - fmax(Y1, bY1) + 1.0;
                    IW = IW > 0.0 ? IW : 0.0;
                    IH = IH > 0.0 ? IH : 0.0;
                    double INTER = IW * IH;
                    double AJ = (bX2 - bX1 + 1.0) * (bY2 - bY1 + 1.0);
                    double IOU = INTER / ((AR + AJ) - INTER);
                    res = IOU > 0.7;
                }
                unsigned long long bb = __ballot(res);
                myw = (t == 2 * k) ? (unsigned)bb : myw;
                myw = (t == 2 * k + 1) ? (unsigned)(bb >> 32) : myw;
            }
        }
        mask[((size_t)img * MROWS + r) * 64 + t] = myw;
    }
}

// K7: sequential-scan greedy NMS, branchless scalar-mirror inner loop.
#define NMS_LOAD(B, G)                                          \
    _Pragma("unroll")                                           \
    for (int s = 0; s < 16; ++s) B[s] = mrow[((G) * 16 + s) * 64];

#define NMS_PROC(B, G, PAR) {                                   \
    int W = (G) >> 1;                                           \
    if ((PAR) == 0) s_cur = (unsigned)__builtin_amdgcn_readlane((int)sup, W); \
    _Pragma("unroll")                                           \
    for (int s = 0; s < 16; ++s) {                              \
        unsigned rb = (unsigned)__builtin_amdgcn_readlane((int)B[s], W); \
        unsigned bit = (s_cur >> (((PAR) << 4) + s)) & 1u;      \
        unsigned am = bit - 1u;  /* alive: ~0, dead: 0 */       \
        s_cur |= rb & am;                                       \
        s_pick |= am & (1u << (((PAR) << 4) + s));              \
        sup |= B[s] & am;                                       \
    }                                                           \
    if ((PAR) == 1) {                                           \
        pickedv = (t == W) ? (int)s_pick : pickedv;             \
        np += __builtin_popcount(s_pick);                       \
        s_pick = 0;                                             \
    }                                                           \
}

__global__ void __launch_bounds__(64) k_nms(const double* __restrict__ boxes,
                                            const float* __restrict__ scores,
                                            const unsigned* __restrict__ negmask,
                                            const unsigned* __restrict__ mask,
                                            float* __restrict__ out) {
    __shared__ int picks[POST];
    __shared__ unsigned wcnt[64];
    __shared__ int tot;
    int img = blockIdx.x;
    int t = threadIdx.x;
    unsigned sup = negmask[img * 64 + t];
    if (t == 62) sup |= 0xFFFF0000u;  // indices 2000..2015 invalid
    if (t == 63) sup = 0xFFFFFFFFu;   // indices 2016..2047 invalid
    const unsigned* mrow = mask + (size_t)img * MROWS * 64 + t;
    unsigned b0[16], b1[16], b2[16], b3[16];
    NMS_LOAD(b0, 0)
    NMS_LOAD(b1, 1)
    NMS_LOAD(b2, 2)
    NMS_LOAD(b3, 3)
    int np = 0;
    unsigned s_cur = 0, s_pick = 0;
    int pickedv = 0;
    // 125 groups of 16 rows (2000). Main loop: groups 0..123; epilogue: 124.
    for (int gg = 0; gg < 124; gg += 4) {
        NMS_PROC(b0, gg + 0, 0) NMS_LOAD(b0, gg + 4)
        NMS_PROC(b1, gg + 1, 1) NMS_LOAD(b1, gg + 5)
        NMS_PROC(b2, gg + 2, 0) NMS_LOAD(b2, gg + 6)
        NMS_PROC(b3, gg + 3, 1) NMS_LOAD(b3, gg + 7)   // max load group 127 < MROWS/16
        if (np >= POST) break;
    }
    if (np < POST) {
        NMS_PROC(b0, 124, 0)   // jj 1984..1999, word 62 low half
        pickedv = (t == 62) ? (int)s_pick : pickedv;
        np += __builtin_popcount(s_pick);
    }
    // epilogue: materialize picks[] from the bitmap (lane W holds word W)
    wcnt[t] = (unsigned)__builtin_popcount((unsigned)pickedv);
    __syncthreads();
    int pre = 0;
    for (int i = 0; i < t; ++i) pre += (int)wcnt[i];
    if (t == 63) tot = pre + (int)wcnt[63];
    __syncthreads();
    unsigned pw = (unsigned)pickedv;
    int rank = pre;
    while (pw) {
        int b = __ffs(pw) - 1;
        pw &= pw - 1;
        if (rank < POST) picks[rank] = t * 32 + b;
        rank++;
    }
    __syncthreads();
    int np_final = tot > POST ? POST : tot;
    float* ob = out + (size_t)img * POST * 4;
    float* os = out + (size_t)NIMG * POST * 4 + (size_t)img * POST;
    for (int k = t; k < POST; k += 64) {
        if (k < np_final) {
            int p = picks[k];
            const double* bp = boxes + ((size_t)img * PRE + p) * 4;
            ob[k * 4 + 0] = (float)bp[0];
            ob[k * 4 + 1] = (float)bp[1];
            ob[k * 4 + 2] = (float)bp[2];
            ob[k * 4 + 3] = (float)bp[3];
            os[k] = scores[img * PRE + p];
        } else {
            ob[k * 4 + 0] = 0.0f; ob[k * 4 + 1] = 0.0f;
            ob[k * 4 + 2] = 0.0f; ob[k * 4 + 3] = 0.0f;
            os[k] = NEGF;
        }
    }
}

extern "C" void kernel_launch(void* const* d_in, const int* in_sizes, int n_in,
                              void* d_out, int out_size, void* d_ws, size_t ws_size,
                              hipStream_t stream) {
    const float* anchors = (const float*)d_in[0];
    const float4* obj4 = (const float4*)d_in[1];
    const float* br = (const float*)d_in[2];
    float* out = (float*)d_out;

    char* ws = (char*)d_ws;
    size_t off = 0;
    auto alloc = [&](size_t bytes) {
        void* p = ws + off;
        off = (off + bytes + 255) & ~(size_t)255;
        return p;
    };
    // zero-initialized region (single fused memset)
    unsigned* hist = (unsigned*)alloc((size_t)NIMG * NBUCKET * 4);
    unsigned* hist2 = (unsigned*)alloc((size_t)NIMG * NBUCKET * 4);
    unsigned* done1 = (unsigned*)alloc((size_t)NIMG * 64 * 4);
    unsigned* done2 = (unsigned*)alloc((size_t)NIMG * 64 * 4);
    unsigned* selcnt = (unsigned*)alloc((size_t)NIMG * 64 * 4);      // one cache line per image
    unsigned* negmask = (unsigned*)alloc((size_t)NIMG * 64 * 4);
    size_t zero_bytes = off;
    // non-zeroed buffers
    unsigned* bsel = (unsigned*)alloc(NIMG * 4);
    unsigned* cntAbove = (unsigned*)alloc(NIMG * 4);
    unsigned* thr32 = (unsigned*)alloc(NIMG * 4);
    unsigned long long* keys = (unsigned long long*)alloc((size_t)NIMG * CAP2 * 8);
    double* boxes = (double*)alloc((size_t)NIMG * PRE * 4 * 8);
    float4* boxesf = (float4*)alloc((size_t)NIMG * PRE * 16);
    float* scores = (float*)alloc((size_t)NIMG * PRE * 4);
    unsigned* mask = (unsigned*)alloc((size_t)NIMG * MROWS * 64 * 4);

    hipMemsetAsync(hist, 0, zero_bytes, stream);

    k_hist<<<dim3(64, NIMG), 256, 0, stream>>>(obj4, hist, bsel, cntAbove, done1);
    k_hist2<<<dim3(64, NIMG), 256, 0, stream>>>(obj4, bsel, cntAbove, hist2, thr32, done2);
    k_compact<<<dim3(64, NIMG), 256, 0, stream>>>(obj4, thr32, selcnt, keys);
    k_sort<<<NIMG, 1024, 0, stream>>>(keys, selcnt);
    k_decode<<<(NIMG * PRE + 255) / 256, 256, 0, stream>>>(anchors, br, keys, boxes, boxesf, scores, negmask);
    k_mask<<<dim3(MBLK, NIMG), 256, 0, stream>>>(boxesf, boxes, mask);
    k_nms<<<NIMG, 64, 0, stream>>>(boxes, scores, negmask, mask, out);
}

// Round 13
// 164.933 us; speedup vs baseline: 1.8621x; 1.7227x over previous
//
#include <hip/hip_runtime.h>
#include <math.h>

#define NIMG 16
#define A 3
#define HW 65536
#define AHW 196608
#define PRE 2000
#define POST 1000
#define CAP2 2048
#define MROWS 2048
#define NBUCKET 2048
#define NEGF (-1e30f)
#define LBUF 256
#define BW 0.01f
#define BD 4.0f
#define MBLK 64

__device__ __forceinline__ unsigned mapf(float x) {
    unsigned u = __float_as_uint(x);
    return (u & 0x80000000u) ? ~u : (u | 0x80000000u);
}

// K1: per-image histogram of top 11 bits of monotone-mapped objectness (float4 loads)
__global__ void __launch_bounds__(256) k_hist(const float4* __restrict__ obj4,
                                              unsigned* __restrict__ hist) {
    __shared__ unsigned lh[NBUCKET];
    int img = blockIdx.y;
    for (int i = threadIdx.x; i < NBUCKET; i += 256) lh[i] = 0;
    __syncthreads();
    const float4* p = obj4 + (size_t)img * (AHW / 4);
    int stride = gridDim.x * 256;
    for (int v = blockIdx.x * 256 + threadIdx.x; v < AHW / 4; v += stride) {
        float4 f = p[v];
        atomicAdd(&lh[mapf(f.x) >> 21], 1u);
        atomicAdd(&lh[mapf(f.y) >> 21], 1u);
        atomicAdd(&lh[mapf(f.z) >> 21], 1u);
        atomicAdd(&lh[mapf(f.w) >> 21], 1u);
    }
    __syncthreads();
    unsigned* gh = hist + img * NBUCKET;
    for (int i = threadIdx.x; i < NBUCKET; i += 256)
        if (lh[i]) atomicAdd(&gh[i], lh[i]);
}

// K2: find coarse threshold bucket B per image; also count strictly above B
__global__ void __launch_bounds__(256) k_thresh(const unsigned* __restrict__ hist,
                                                unsigned* __restrict__ bsel,
                                                unsigned* __restrict__ cntAbove) {
    __shared__ unsigned part[256];
    int img = blockIdx.x;
    int t = threadIdx.x;
    const unsigned* gh = hist + img * NBUCKET;
    unsigned s = 0;
    for (int k = 0; k < 8; ++k) s += gh[t * 8 + k];
    part[t] = s;
    __syncthreads();
    if (t == 0) {
        unsigned cum = 0;
        int done = 0;
        for (int c = 255; c >= 0 && !done; --c) {
            if (cum + part[c] >= PRE) {
                for (int i = c * 8 + 7; i >= c * 8; --i) {
                    unsigned h = gh[i];
                    if (cum + h >= PRE) { bsel[img] = (unsigned)i; cntAbove[img] = cum; done = 1; break; }
                    cum += h;
                }
            } else {
                cum += part[c];
            }
        }
    }
}

// K3: histogram of next 11 bits within coarse bucket B (float4 loads)
__global__ void __launch_bounds__(256) k_hist2(const float4* __restrict__ obj4,
                                               const unsigned* __restrict__ bsel,
                                               unsigned* __restrict__ hist2) {
    __shared__ unsigned lh[NBUCKET];
    int img = blockIdx.y;
    unsigned B = bsel[img];
    for (int i = threadIdx.x; i < NBUCKET; i += 256) lh[i] = 0;
    __syncthreads();
    const float4* p = obj4 + (size_t)img * (AHW / 4);
    int stride = gridDim.x * 256;
    for (int v = blockIdx.x * 256 + threadIdx.x; v < AHW / 4; v += stride) {
        float4 f = p[v];
        unsigned m0 = mapf(f.x), m1 = mapf(f.y), m2 = mapf(f.z), m3 = mapf(f.w);
        if ((m0 >> 21) == B) atomicAdd(&lh[(m0 >> 10) & 0x7FF], 1u);
        if ((m1 >> 21) == B) atomicAdd(&lh[(m1 >> 10) & 0x7FF], 1u);
        if ((m2 >> 21) == B) atomicAdd(&lh[(m2 >> 10) & 0x7FF], 1u);
        if ((m3 >> 21) == B) atomicAdd(&lh[(m3 >> 10) & 0x7FF], 1u);
    }
    __syncthreads();
    unsigned* gh = hist2 + img * NBUCKET;
    for (int i = threadIdx.x; i < NBUCKET; i += 256)
        if (lh[i]) atomicAdd(&gh[i], lh[i]);
}

// K4: refine to 22-bit threshold
__global__ void __launch_bounds__(256) k_thresh2(const unsigned* __restrict__ hist2,
                                                 const unsigned* __restrict__ bsel,
                                                 const unsigned* __restrict__ cntAbove,
                                                 unsigned* __restrict__ thr32) {
    __shared__ unsigned part[256];
    int img = blockIdx.x;
    int t = threadIdx.x;
    const unsigned* gh = hist2 + img * NBUCKET;
    unsigned s = 0;
    for (int k = 0; k < 8; ++k) s += gh[t * 8 + k];
    part[t] = s;
    __syncthreads();
    if (t == 0) {
        unsigned cum = cntAbove[img];
        unsigned B = bsel[img];
        int done = 0;
        for (int c = 255; c >= 0 && !done; --c) {
            if (cum + part[c] >= PRE) {
                for (int i = c * 8 + 7; i >= c * 8; --i) {
                    unsigned h = gh[i];
                    if (cum + h >= PRE) { thr32[img] = (B << 21) | ((unsigned)i << 10); done = 1; break; }
                    cum += h;
                }
            } else {
                cum += part[c];
            }
        }
    }
}

// K5: compact candidates with m >= thr. Two-level: LDS staging + one global
// atomic per block (selcnt padded to a private cache line per image).
__global__ void __launch_bounds__(256) k_compact(const float4* __restrict__ obj4,
                                                 const unsigned* __restrict__ thr32,
                                                 unsigned* __restrict__ selcnt,
                                                 unsigned long long* __restrict__ keys) {
    __shared__ unsigned long long lbuf[LBUF];
    __shared__ unsigned lcnt, gbase;
    int img = blockIdx.y;
    unsigned thr = thr32[img];
    if (threadIdx.x == 0) lcnt = 0;
    __syncthreads();
    const float4* p = obj4 + (size_t)img * (AHW / 4);
    int v0 = blockIdx.x * 768;
    #pragma unroll
    for (int it = 0; it < 3; ++it) {
        int v = v0 + it * 256 + threadIdx.x;
        float4 f = p[v];
        int jb = v * 4;
        #pragma unroll
        for (int k = 0; k < 4; ++k) {
            float x = k == 0 ? f.x : (k == 1 ? f.y : (k == 2 ? f.z : f.w));
            unsigned m = mapf(x);
            if (m >= thr) {
                int j = jb + k;
                int a = j >> 16;
                int hw = j & 65535;
                unsigned idx = (unsigned)(hw * A + a);
                unsigned pos = atomicAdd(&lcnt, 1u);
                if (pos < LBUF)
                    lbuf[pos] = ((unsigned long long)m << 32) | (unsigned)(~idx);
            }
        }
    }
    __syncthreads();
    unsigned n = lcnt > LBUF ? LBUF : lcnt;
    if (threadIdx.x == 0) gbase = atomicAdd(&selcnt[img * 64], n);
    __syncthreads();
    if (threadIdx.x < n) {
        unsigned pos = gbase + threadIdx.x;
        if (pos < CAP2)
            keys[(size_t)img * CAP2 + pos] = lbuf[threadIdx.x];
    }
}

// K6: per-image bitonic sort, descending. Tail beyond the valid count is
// padded with 0 keys in LDS (keys buffer itself is not zeroed).
__global__ void __launch_bounds__(1024) k_sort(unsigned long long* __restrict__ keys,
                                               const unsigned* __restrict__ selcnt) {
    __shared__ unsigned long long s[CAP2];
    int img = blockIdx.x;
    unsigned cnt = selcnt[img * 64];
    if (cnt > CAP2) cnt = CAP2;
    unsigned long long* g = keys + (size_t)img * CAP2;
    for (int i = threadIdx.x; i < CAP2; i += 1024)
        s[i] = (i < (int)cnt) ? g[i] : 0ULL;
    __syncthreads();
    for (int k2 = 2; k2 <= CAP2; k2 <<= 1) {
        for (int j = k2 >> 1; j > 0; j >>= 1) {
            for (int i = threadIdx.x; i < CAP2; i += 1024) {
                int ixj = i ^ j;
                if (ixj > i) {
                    unsigned long long a = s[i], b = s[ixj];
                    bool up = ((i & k2) == 0);
                    if (up ? (a < b) : (a > b)) { s[i] = b; s[ixj] = a; }
                }
            }
            __syncthreads();
        }
    }
    for (int i = threadIdx.x; i < PRE; i += 1024) g[i] = s[i];
}

// K7: decode boxes (f64), clip, MIN_SIZE filter, sigmoid score.
// Writes f64 boxes (exact path) AND f32 boxes (screen path).
__global__ void k_decode(const float* __restrict__ anchors, const float* __restrict__ br,
                         const unsigned long long* __restrict__ keys,
                         double* __restrict__ boxes, float4* __restrict__ boxesf,
                         float* __restrict__ scores, unsigned* __restrict__ negmask) {
    int g = blockIdx.x * blockDim.x + threadIdx.x;
    if (g >= NIMG * PRE) return;
    int img = g / PRE, r = g % PRE;
    unsigned long long key = keys[(size_t)img * CAP2 + r];
    unsigned m = (unsigned)(key >> 32);
    unsigned idx = ~(unsigned)key;
    unsigned u = (m & 0x80000000u) ? (m ^ 0x80000000u) : ~m;
    float x = __uint_as_float(u);
    double sc = 1.0 / (1.0 + exp(-(double)x));
    int a = idx % 3;
    int hw = idx / 3;
    const float* anc = anchors + ((size_t)img * AHW + idx) * 4;
    double ax1 = anc[0], ay1 = anc[1], ax2 = anc[2], ay2 = anc[3];
    double aw = ax2 - ax1 + 1.0, ah = ay2 - ay1 + 1.0;
    double cx = ax1 + 0.5 * aw, cy = ay1 + 0.5 * ah;
    const float* bp = br + (size_t)img * 12 * HW + (size_t)a * 4 * HW + hw;
    double dx = bp[0];
    double dy = bp[(size_t)HW];
    double dw = bp[(size_t)2 * HW];
    double dh = bp[(size_t)3 * HW];
    const double CLIPV = 4.135166556742356; // log(1000/16)
    dw = fmin(dw, CLIPV); dh = fmin(dh, CLIPV);
    double pcx = dx * aw + cx, pcy = dy * ah + cy;
    double pw = exp(dw) * aw, ph = exp(dh) * ah;
    double x1 = pcx - 0.5 * pw, y1 = pcy - 0.5 * ph;
    double x2 = pcx + 0.5 * pw - 1.0, y2 = pcy + 0.5 * ph - 1.0;
    x1 = fmin(fmax(x1, 0.0), 1023.0);
    y1 = fmin(fmax(y1, 0.0), 1023.0);
    x2 = fmin(fmax(x2, 0.0), 1023.0);
    y2 = fmin(fmax(y2, 0.0), 1023.0);
    bool keep = (x2 - x1 + 1.0 >= 0.0) && (y2 - y1 + 1.0 >= 0.0);
    double* bo = boxes + ((size_t)img * PRE + r) * 4;
    bo[0] = x1; bo[1] = y1; bo[2] = x2; bo[3] = y2;
    float4 bf;
    bf.x = (float)x1; bf.y = (float)y1; bf.z = (float)x2; bf.w = (float)y2;
    boxesf[(size_t)img * PRE + r] = bf;
    scores[img * PRE + r] = keep ? (float)sc : NEGF;
    if (!keep) atomicOr(&negmask[img * 64 + (r >> 5)], 1u << (r & 31));
}

// K8: upper-triangle IoU suppression bitmask. BRANCH-FREE f32 screen inner
// loop (predication only); rare rows with borderline pairs are rebuilt in a
// per-row exact fixup pass (f64, reference formula). LDS: float4 box + 0.7*area,
// padded to 2048 with sentinels. Strided rows for balance; 40960B -> 4 blk/CU.
__global__ void __launch_bounds__(256) k_mask(const float4* __restrict__ boxesf,
                                              const double* __restrict__ boxes,
                                              unsigned* __restrict__ mask) {
    __shared__ float4 sb[MROWS];
    __shared__ float sa7[MROWS];
    int img = blockIdx.y;
    int tid = threadIdx.x;
    int wave = tid >> 6, t = tid & 63;
    const float4* fb = boxesf + (size_t)img * PRE;
    for (int i = tid; i < MROWS; i += 256) {
        float4 b;
        if (i < PRE) {
            b = fb[i];
        } else {
            b.x = 1e8f; b.y = 1e8f; b.z = -1e8f; b.w = -1e8f;  // sentinel: never overlaps
        }
        sb[i] = b;
        sa7[i] = 0.7f * ((b.z - b.x + 1.0f) * (b.w - b.y + 1.0f));
    }
    __syncthreads();
    const double* base64 = boxes + (size_t)img * PRE * 4;
    for (int rr = 0; rr < 8; ++rr) {
        int r = blockIdx.x + MBLK * (rr * 4 + wave);   // strided row map
        if (r >= PRE) break;
        float4 p = sb[r];
        float a7r = sa7[r];
        int kmin = r >> 6;
        unsigned myw = 0;
        bool anyneed = false;
        for (int k = kmin; k < 32; ++k) {
            int col = 64 * k + t;
            float4 q = sb[col];
            float iw = fminf(p.z, q.z) - fmaxf(p.x, q.x) + 1.0f;
            float ih = fminf(p.w, q.w) - fmaxf(p.y, q.y) + 1.0f;
            float inter = iw * ih;
            float d = fmaf(1.7f, inter, -(a7r + sa7[col]));
            bool ov = (iw > -BW) & (ih > -BW);
            bool need = ov & ((iw < BW) | (ih < BW) | (fabsf(d) < BD));
            bool res = ov & (d > 0.0f);
            anyneed |= need;
            unsigned long long bb = __ballot(res);
            myw = (t == 2 * k) ? (unsigned)bb : myw;
            myw = (t == 2 * k + 1) ? (unsigned)(bb >> 32) : myw;
        }
        if (__any(anyneed)) {
            // rare: rebuild row exactly, resolving borderline pairs in f64
            const double* ri = base64 + (size_t)r * 4;
            double X1 = ri[0], Y1 = ri[1], X2 = ri[2], Y2 = ri[3];
            double AR = (X2 - X1 + 1.0) * (Y2 - Y1 + 1.0);
            myw = 0;
            for (int k = kmin; k < 32; ++k) {
                int col = 64 * k + t;
                float4 q = sb[col];
                float iw = fminf(p.z, q.z) - fmaxf(p.x, q.x) + 1.0f;
                float ih = fminf(p.w, q.w) - fmaxf(p.y, q.y) + 1.0f;
                float inter = iw * ih;
                float d = fmaf(1.7f, inter, -(a7r + sa7[col]));
                bool ov = (iw > -BW) & (ih > -BW);
                bool need = ov & ((iw < BW) | (ih < BW) | (fabsf(d) < BD));
                bool res = ov & (d > 0.0f);
                if (need) {   // col < PRE guaranteed (sentinels can't set need)
                    const double* rj = base64 + (size_t)col * 4;
                    double bX1 = rj[0], bY1 = rj[1], bX2 = rj[2], bY2 = rj[3];
                    double IW = fmin(X2, bX2) - fmax(X1, bX1) + 1.0;
                    double IH = fmin(Y2, bY2) - fmax(Y1, bY1) + 1.0;
                    IW = IW > 0.0 ? IW : 0.0;
                    IH = IH > 0.0 ? IH : 0.0;
                    double INTER = IW * IH;
                    double AJ = (bX2 - bX1 + 1.0) * (bY2 - bY1 + 1.0);
                    double IOU = INTER / ((AR + AJ) - INTER);
                    res = IOU > 0.7;
                }
                unsigned long long bb = __ballot(res);
                myw = (t == 2 * k) ? (unsigned)bb : myw;
                myw = (t == 2 * k + 1) ? (unsigned)(bb >> 32) : myw;
            }
        }
        mask[((size_t)img * MROWS + r) * 64 + t] = myw;
    }
}

// K9: sequential-scan greedy NMS, branchless scalar-mirror inner loop.
#define NMS_LOAD(B, G)                                          \
    _Pragma("unroll")                                           \
    for (int s = 0; s < 16; ++s) B[s] = mrow[((G) * 16 + s) * 64];

#define NMS_PROC(B, G, PAR) {                                   \
    int W = (G) >> 1;                                           \
    if ((PAR) == 0) s_cur = (unsigned)__builtin_amdgcn_readlane((int)sup, W); \
    _Pragma("unroll")                                           \
    for (int s = 0; s < 16; ++s) {                              \
        unsigned rb = (unsigned)__builtin_amdgcn_readlane((int)B[s], W); \
        unsigned bit = (s_cur >> (((PAR) << 4) + s)) & 1u;      \
        unsigned am = bit - 1u;  /* alive: ~0, dead: 0 */       \
        s_cur |= rb & am;                                       \
        s_pick |= am & (1u << (((PAR) << 4) + s));              \
        sup |= B[s] & am;                                       \
    }                                                           \
    if ((PAR) == 1) {                                           \
        pickedv = (t == W) ? (int)s_pick : pickedv;             \
        np += __builtin_popcount(s_pick);                       \
        s_pick = 0;                                             \
    }                                                           \
}

__global__ void __launch_bounds__(64) k_nms(const double* __restrict__ boxes,
                                            const float* __restrict__ scores,
                                            const unsigned* __restrict__ negmask,
                                            const unsigned* __restrict__ mask,
                                            float* __restrict__ out) {
    __shared__ int picks[POST];
    __shared__ unsigned wcnt[64];
    __shared__ int tot;
    int img = blockIdx.x;
    int t = threadIdx.x;
    unsigned sup = negmask[img * 64 + t];
    if (t == 62) sup |= 0xFFFF0000u;  // indices 2000..2015 invalid
    if (t == 63) sup = 0xFFFFFFFFu;   // indices 2016..2047 invalid
    const unsigned* mrow = mask + (size_t)img * MROWS * 64 + t;
    unsigned b0[16], b1[16], b2[16], b3[16];
    NMS_LOAD(b0, 0)
    NMS_LOAD(b1, 1)
    NMS_LOAD(b2, 2)
    NMS_LOAD(b3, 3)
    int np = 0;
    unsigned s_cur = 0, s_pick = 0;
    int pickedv = 0;
    // 125 groups of 16 rows (2000). Main loop: groups 0..123; epilogue: 124.
    for (int gg = 0; gg < 124; gg += 4) {
        NMS_PROC(b0, gg + 0, 0) NMS_LOAD(b0, gg + 4)
        NMS_PROC(b1, gg + 1, 1) NMS_LOAD(b1, gg + 5)
        NMS_PROC(b2, gg + 2, 0) NMS_LOAD(b2, gg + 6)
        NMS_PROC(b3, gg + 3, 1) NMS_LOAD(b3, gg + 7)   // max load group 127 < MROWS/16
        if (np >= POST) break;
    }
    if (np < POST) {
        NMS_PROC(b0, 124, 0)   // jj 1984..1999, word 62 low half
        pickedv = (t == 62) ? (int)s_pick : pickedv;
        np += __builtin_popcount(s_pick);
    }
    // epilogue: materialize picks[] from the bitmap (lane W holds word W)
    wcnt[t] = (unsigned)__builtin_popcount((unsigned)pickedv);
    __syncthreads();
    int pre = 0;
    for (int i = 0; i < t; ++i) pre += (int)wcnt[i];
    if (t == 63) tot = pre + (int)wcnt[63];
    __syncthreads();
    unsigned pw = (unsigned)pickedv;
    int rank = pre;
    while (pw) {
        int b = __ffs(pw) - 1;
        pw &= pw - 1;
        if (rank < POST) picks[rank] = t * 32 + b;
        rank++;
    }
    __syncthreads();
    int np_final = tot > POST ? POST : tot;
    float* ob = out + (size_t)img * POST * 4;
    float* os = out + (size_t)NIMG * POST * 4 + (size_t)img * POST;
    for (int k = t; k < POST; k += 64) {
        if (k < np_final) {
            int p = picks[k];
            const double* bp = boxes + ((size_t)img * PRE + p) * 4;
            ob[k * 4 + 0] = (float)bp[0];
            ob[k * 4 + 1] = (float)bp[1];
            ob[k * 4 + 2] = (float)bp[2];
            ob[k * 4 + 3] = (float)bp[3];
            os[k] = scores[img * PRE + p];
        } else {
            ob[k * 4 + 0] = 0.0f; ob[k * 4 + 1] = 0.0f;
            ob[k * 4 + 2] = 0.0f; ob[k * 4 + 3] = 0.0f;
            os[k] = NEGF;
        }
    }
}

extern "C" void kernel_launch(void* const* d_in, const int* in_sizes, int n_in,
                              void* d_out, int out_size, void* d_ws, size_t ws_size,
                              hipStream_t stream) {
    const float* anchors = (const float*)d_in[0];
    const float4* obj4 = (const float4*)d_in[1];
    const float* br = (const float*)d_in[2];
    float* out = (float*)d_out;

    char* ws = (char*)d_ws;
    size_t off = 0;
    auto alloc = [&](size_t bytes) {
        void* p = ws + off;
        off = (off + bytes + 255) & ~(size_t)255;
        return p;
    };
    // zero-initialized region (single fused memset): hist..negmask
    unsigned* hist = (unsigned*)alloc((size_t)NIMG * NBUCKET * 4);
    unsigned* hist2 = (unsigned*)alloc((size_t)NIMG * NBUCKET * 4);
    unsigned* bsel = (unsigned*)alloc(NIMG * 4);
    unsigned* cntAbove = (unsigned*)alloc(NIMG * 4);
    unsigned* thr32 = (unsigned*)alloc(NIMG * 4);
    unsigned* selcnt = (unsigned*)alloc((size_t)NIMG * 64 * 4);      // one cache line per image
    unsigned* negmask = (unsigned*)alloc((size_t)NIMG * 64 * 4);
    size_t zero_bytes = off;
    // non-zeroed buffers
    unsigned long long* keys = (unsigned long long*)alloc((size_t)NIMG * CAP2 * 8);
    double* boxes = (double*)alloc((size_t)NIMG * PRE * 4 * 8);
    float4* boxesf = (float4*)alloc((size_t)NIMG * PRE * 16);
    float* scores = (float*)alloc((size_t)NIMG * PRE * 4);
    unsigned* mask = (unsigned*)alloc((size_t)NIMG * MROWS * 64 * 4);

    hipMemsetAsync(hist, 0, zero_bytes, stream);

    k_hist<<<dim3(64, NIMG), 256, 0, stream>>>(obj4, hist);
    k_thresh<<<NIMG, 256, 0, stream>>>(hist, bsel, cntAbove);
    k_hist2<<<dim3(64, NIMG), 256, 0, stream>>>(obj4, bsel, hist2);
    k_thresh2<<<NIMG, 256, 0, stream>>>(hist2, bsel, cntAbove, thr32);
    k_compact<<<dim3(64, NIMG), 256, 0, stream>>>(obj4, thr32, selcnt, keys);
    k_sort<<<NIMG, 1024, 0, stream>>>(keys, selcnt);
    k_decode<<<(NIMG * PRE + 255) / 256, 256, 0, stream>>>(anchors, br, keys, boxes, boxesf, scores, negmask);
    k_mask<<<dim3(MBLK, NIMG), 256, 0, stream>>>(boxesf, boxes, mask);
    k_nms<<<NIMG, 64, 0, stream>>>(boxes, scores, negmask, mask, out);
}

// Round 14
// 146.229 us; speedup vs baseline: 2.1003x; 1.1279x over previous
//
#include <hip/hip_runtime.h>
#include <math.h>

#define NIMG 16
#define A 3
#define HW 65536
#define AHW 196608
#define PRE 2000
#define POST 1000
#define CAP2 2048
#define MROWS 2048
#define NBUCKET 2048
#define NEGF (-1e30f)
#define LBUF 256
#define BW 0.01f
#define BD 4.0f
#define NQUAD 500      // 2000 rows / 4
#define QWAVES 250     // wave-slots: each handles quads (g, 499-g)

__device__ __forceinline__ unsigned mapf(float x) {
    unsigned u = __float_as_uint(x);
    return (u & 0x80000000u) ? ~u : (u | 0x80000000u);
}

// K1: per-image histogram of top 11 bits of monotone-mapped objectness (float4 loads)
__global__ void __launch_bounds__(256) k_hist(const float4* __restrict__ obj4,
                                              unsigned* __restrict__ hist) {
    __shared__ unsigned lh[NBUCKET];
    int img = blockIdx.y;
    for (int i = threadIdx.x; i < NBUCKET; i += 256) lh[i] = 0;
    __syncthreads();
    const float4* p = obj4 + (size_t)img * (AHW / 4);
    int stride = gridDim.x * 256;
    for (int v = blockIdx.x * 256 + threadIdx.x; v < AHW / 4; v += stride) {
        float4 f = p[v];
        atomicAdd(&lh[mapf(f.x) >> 21], 1u);
        atomicAdd(&lh[mapf(f.y) >> 21], 1u);
        atomicAdd(&lh[mapf(f.z) >> 21], 1u);
        atomicAdd(&lh[mapf(f.w) >> 21], 1u);
    }
    __syncthreads();
    unsigned* gh = hist + img * NBUCKET;
    for (int i = threadIdx.x; i < NBUCKET; i += 256)
        if (lh[i]) atomicAdd(&gh[i], lh[i]);
}

// Parallel threshold scan: suffix-sum over 256 coarse chunks (Hillis-Steele),
// unique crossing thread does the <=8-bucket descent. Replaces the t0-serial
// 256-iteration dependent-load chain.
__device__ __forceinline__ void thresh_scan_par(const unsigned* __restrict__ gh,
                                                unsigned cum0,
                                                unsigned* part, unsigned* sfx,
                                                unsigned* outB, unsigned* outCum) {
    int t = threadIdx.x;
    unsigned s = 0;
    for (int k = 0; k < 8; ++k) s += gh[t * 8 + k];
    part[t] = s;
    sfx[t] = s;
    __syncthreads();
    for (int d = 1; d < 256; d <<= 1) {
        unsigned v = (t + d < 256) ? sfx[t + d] : 0u;
        __syncthreads();
        sfx[t] += v;
        __syncthreads();
    }
    unsigned inc = sfx[t], exc = inc - part[t];
    if (cum0 + inc >= PRE && cum0 + exc < PRE) {   // exactly one thread
        unsigned cum = cum0 + exc;
        for (int i = t * 8 + 7; i >= t * 8; --i) {
            unsigned h = gh[i];
            if (cum + h >= PRE) { *outB = (unsigned)i; *outCum = cum; break; }
            cum += h;
        }
    }
}

// K2: coarse threshold bucket B per image + count strictly above B
__global__ void __launch_bounds__(256) k_thresh(const unsigned* __restrict__ hist,
                                                unsigned* __restrict__ bsel,
                                                unsigned* __restrict__ cntAbove) {
    __shared__ unsigned part[256], sfx[256];
    int img = blockIdx.x;
    thresh_scan_par(hist + img * NBUCKET, 0u, part, sfx, &bsel[img], &cntAbove[img]);
}

// K3: histogram of next 11 bits within coarse bucket B (float4 loads)
__global__ void __launch_bounds__(256) k_hist2(const float4* __restrict__ obj4,
                                               const unsigned* __restrict__ bsel,
                                               unsigned* __restrict__ hist2) {
    __shared__ unsigned lh[NBUCKET];
    int img = blockIdx.y;
    unsigned B = bsel[img];
    for (int i = threadIdx.x; i < NBUCKET; i += 256) lh[i] = 0;
    __syncthreads();
    const float4* p = obj4 + (size_t)img * (AHW / 4);
    int stride = gridDim.x * 256;
    for (int v = blockIdx.x * 256 + threadIdx.x; v < AHW / 4; v += stride) {
        float4 f = p[v];
        unsigned m0 = mapf(f.x), m1 = mapf(f.y), m2 = mapf(f.z), m3 = mapf(f.w);
        if ((m0 >> 21) == B) atomicAdd(&lh[(m0 >> 10) & 0x7FF], 1u);
        if ((m1 >> 21) == B) atomicAdd(&lh[(m1 >> 10) & 0x7FF], 1u);
        if ((m2 >> 21) == B) atomicAdd(&lh[(m2 >> 10) & 0x7FF], 1u);
        if ((m3 >> 21) == B) atomicAdd(&lh[(m3 >> 10) & 0x7FF], 1u);
    }
    __syncthreads();
    unsigned* gh = hist2 + img * NBUCKET;
    for (int i = threadIdx.x; i < NBUCKET; i += 256)
        if (lh[i]) atomicAdd(&gh[i], lh[i]);
}

// K4: refine to 22-bit threshold
__global__ void __launch_bounds__(256) k_thresh2(const unsigned* __restrict__ hist2,
                                                 const unsigned* __restrict__ bsel,
                                                 const unsigned* __restrict__ cntAbove,
                                                 unsigned* __restrict__ thr32) {
    __shared__ unsigned part[256], sfx[256];
    __shared__ unsigned bk, cumdummy;
    int img = blockIdx.x;
    thresh_scan_par(hist2 + img * NBUCKET, cntAbove[img], part, sfx, &bk, &cumdummy);
    __syncthreads();
    if (threadIdx.x == 0) thr32[img] = (bsel[img] << 21) | (bk << 10);
}

// K5: compact candidates with m >= thr. Two-level: LDS staging + one global
// atomic per block (selcnt padded to a private cache line per image).
__global__ void __launch_bounds__(256) k_compact(const float4* __restrict__ obj4,
                                                 const unsigned* __restrict__ thr32,
                                                 unsigned* __restrict__ selcnt,
                                                 unsigned long long* __restrict__ keys) {
    __shared__ unsigned long long lbuf[LBUF];
    __shared__ unsigned lcnt, gbase;
    int img = blockIdx.y;
    unsigned thr = thr32[img];
    if (threadIdx.x == 0) lcnt = 0;
    __syncthreads();
    const float4* p = obj4 + (size_t)img * (AHW / 4);
    int v0 = blockIdx.x * 768;
    #pragma unroll
    for (int it = 0; it < 3; ++it) {
        int v = v0 + it * 256 + threadIdx.x;
        float4 f = p[v];
        int jb = v * 4;
        #pragma unroll
        for (int k = 0; k < 4; ++k) {
            float x = k == 0 ? f.x : (k == 1 ? f.y : (k == 2 ? f.z : f.w));
            unsigned m = mapf(x);
            if (m >= thr) {
                int j = jb + k;
                int a = j >> 16;
                int hw = j & 65535;
                unsigned idx = (unsigned)(hw * A + a);
                unsigned pos = atomicAdd(&lcnt, 1u);
                if (pos < LBUF)
                    lbuf[pos] = ((unsigned long long)m << 32) | (unsigned)(~idx);
            }
        }
    }
    __syncthreads();
    unsigned n = lcnt > LBUF ? LBUF : lcnt;
    if (threadIdx.x == 0) gbase = atomicAdd(&selcnt[img * 64], n);
    __syncthreads();
    if (threadIdx.x < n) {
        unsigned pos = gbase + threadIdx.x;
        if (pos < CAP2)
            keys[(size_t)img * CAP2 + pos] = lbuf[threadIdx.x];
    }
}

// K6: per-image bitonic sort, descending. Tail beyond the valid count is
// padded with 0 keys in LDS (keys buffer itself is not zeroed).
__global__ void __launch_bounds__(1024) k_sort(unsigned long long* __restrict__ keys,
                                               const unsigned* __restrict__ selcnt) {
    __shared__ unsigned long long s[CAP2];
    int img = blockIdx.x;
    unsigned cnt = selcnt[img * 64];
    if (cnt > CAP2) cnt = CAP2;
    unsigned long long* g = keys + (size_t)img * CAP2;
    for (int i = threadIdx.x; i < CAP2; i += 1024)
        s[i] = (i < (int)cnt) ? g[i] : 0ULL;
    __syncthreads();
    for (int k2 = 2; k2 <= CAP2; k2 <<= 1) {
        for (int j = k2 >> 1; j > 0; j >>= 1) {
            for (int i = threadIdx.x; i < CAP2; i += 1024) {
                int ixj = i ^ j;
                if (ixj > i) {
                    unsigned long long a = s[i], b = s[ixj];
                    bool up = ((i & k2) == 0);
                    if (up ? (a < b) : (a > b)) { s[i] = b; s[ixj] = a; }
                }
            }
            __syncthreads();
        }
    }
    for (int i = threadIdx.x; i < PRE; i += 1024) g[i] = s[i];
}

// K7: decode boxes (f64), clip, MIN_SIZE filter, sigmoid score.
// Writes f64 boxes (exact path) AND f32 boxes (screen path).
__global__ void k_decode(const float* __restrict__ anchors, const float* __restrict__ br,
                         const unsigned long long* __restrict__ keys,
                         double* __restrict__ boxes, float4* __restrict__ boxesf,
                         float* __restrict__ scores, unsigned* __restrict__ negmask) {
    int g = blockIdx.x * blockDim.x + threadIdx.x;
    if (g >= NIMG * PRE) return;
    int img = g / PRE, r = g % PRE;
    unsigned long long key = keys[(size_t)img * CAP2 + r];
    unsigned m = (unsigned)(key >> 32);
    unsigned idx = ~(unsigned)key;
    unsigned u = (m & 0x80000000u) ? (m ^ 0x80000000u) : ~m;
    float x = __uint_as_float(u);
    double sc = 1.0 / (1.0 + exp(-(double)x));
    int a = idx % 3;
    int hw = idx / 3;
    const float* anc = anchors + ((size_t)img * AHW + idx) * 4;
    double ax1 = anc[0], ay1 = anc[1], ax2 = anc[2], ay2 = anc[3];
    double aw = ax2 - ax1 + 1.0, ah = ay2 - ay1 + 1.0;
    double cx = ax1 + 0.5 * aw, cy = ay1 + 0.5 * ah;
    const float* bp = br + (size_t)img * 12 * HW + (size_t)a * 4 * HW + hw;
    double dx = bp[0];
    double dy = bp[(size_t)HW];
    double dw = bp[(size_t)2 * HW];
    double dh = bp[(size_t)3 * HW];
    const double CLIPV = 4.135166556742356; // log(1000/16)
    dw = fmin(dw, CLIPV); dh = fmin(dh, CLIPV);
    double pcx = dx * aw + cx, pcy = dy * ah + cy;
    double pw = exp(dw) * aw, ph = exp(dh) * ah;
    double x1 = pcx - 0.5 * pw, y1 = pcy - 0.5 * ph;
    double x2 = pcx + 0.5 * pw - 1.0, y2 = pcy + 0.5 * ph - 1.0;
    x1 = fmin(fmax(x1, 0.0), 1023.0);
    y1 = fmin(fmax(y1, 0.0), 1023.0);
    x2 = fmin(fmax(x2, 0.0), 1023.0);
    y2 = fmin(fmax(y2, 0.0), 1023.0);
    bool keep = (x2 - x1 + 1.0 >= 0.0) && (y2 - y1 + 1.0 >= 0.0);
    double* bo = boxes + ((size_t)img * PRE + r) * 4;
    bo[0] = x1; bo[1] = y1; bo[2] = x2; bo[3] = y2;
    float4 bf;
    bf.x = (float)x1; bf.y = (float)y1; bf.z = (float)x2; bf.w = (float)y2;
    boxesf[(size_t)img * PRE + r] = bf;
    scores[img * PRE + r] = keep ? (float)sc : NEGF;
    if (!keep) atomicOr(&negmask[img * 64 + (r >> 5)], 1u << (r & 31));
}

// exact f64 rebuild of one mask row (rare path)
__device__ __noinline__ unsigned fixup_row(const double* __restrict__ base64,
                                           const float4* sbp, const float* sa7p,
                                           int r, int t, int kmin,
                                           float4 P, float Arow) {
    const double* ri = base64 + (size_t)r * 4;
    double X1 = ri[0], Y1 = ri[1], X2 = ri[2], Y2 = ri[3];
    double AR = (X2 - X1 + 1.0) * (Y2 - Y1 + 1.0);
    unsigned myw = 0;
    for (int k = kmin; k < 32; ++k) {
        int col = 64 * k + t;
        float4 q = sbp[col];
        float iw = fminf(P.z, q.z) - fmaxf(P.x, q.x) + 1.0f;
        float ih = fminf(P.w, q.w) - fmaxf(P.y, q.y) + 1.0f;
        float inter = iw * ih;
        float d = fmaf(1.7f, inter, -(Arow + sa7p[col]));
        bool ov = (iw > -BW) & (ih > -BW);
        bool need = ov & ((iw < BW) | (ih < BW) | (fabsf(d) < BD));
        bool res = ov & (d > 0.0f);
        if (need) {   // col < PRE guaranteed (sentinels can't set need)
            const double* rj = base64 + (size_t)col * 4;
            double bX1 = rj[0], bY1 = rj[1], bX2 = rj[2], bY2 = rj[3];
            double IW = fmin(X2, bX2) - fmax(X1, bX1) + 1.0;
            double IH = fmin(Y2, bY2) - fmax(Y1, bY1) + 1.0;
            IW = IW > 0.0 ? IW : 0.0;
            IH = IH > 0.0 ? IH : 0.0;
            double INTER = IW * IH;
            double AJ = (bX2 - bX1 + 1.0) * (bY2 - bY1 + 1.0);
            double IOU = INTER / ((AR + AJ) - INTER);
            res = IOU > 0.7;
        }
        unsigned long long bb = __ballot(res);
        myw = (t == 2 * k) ? (unsigned)bb : myw;
        myw = (t == 2 * k + 1) ? (unsigned)(bb >> 32) : myw;
    }
    return myw;
}

// K8: upper-triangle IoU suppression bitmask, 4-ROW REGISTER BLOCKING.
// Each wave owns row-quads (4 consecutive rows share identical kmin since a
// quad never straddles a 64-boundary); per 64-column step the LDS reads
// (b128 box + b32 area) and the t==2k selects are amortized over 4 rows.
// Wave g handles quads (g, 499-g) -> balanced 33+-1 words per wave.
#define ROWOP(P, Arow, wreg, nflag)                                \
    {                                                              \
        float iw = fminf(P.z, Q.z) - fmaxf(P.x, Q.x) + 1.0f;       \
        float ih = fminf(P.w, Q.w) - fmaxf(P.y, Q.y) + 1.0f;       \
        float inter = iw * ih;                                     \
        float d = fmaf(1.7f, inter, -(Arow + Ac));                 \
        bool ov = (iw > -BW) & (ih > -BW);                         \
        nflag |= ov & ((iw < BW) | (ih < BW) | (fabsf(d) < BD));   \
        bool res = ov & (d > 0.0f);                                \
        unsigned long long bb = __ballot(res);                     \
        wreg = (t == 2 * k) ? (unsigned)bb : wreg;                 \
        wreg = (t == 2 * k + 1) ? (unsigned)(bb >> 32) : wreg;     \
    }

__global__ void __launch_bounds__(256) k_mask(const float4* __restrict__ boxesf,
                                              const double* __restrict__ boxes,
                                              unsigned* __restrict__ mask) {
    __shared__ float4 sb[MROWS];
    __shared__ float sa7[MROWS];
    int img = blockIdx.y;
    int tid = threadIdx.x;
    int wave = tid >> 6, t = tid & 63;
    const float4* fb = boxesf + (size_t)img * PRE;
    for (int i = tid; i < MROWS; i += 256) {
        float4 b;
        if (i < PRE) {
            b = fb[i];
        } else {
            b.x = 1e8f; b.y = 1e8f; b.z = -1e8f; b.w = -1e8f;  // sentinel: never overlaps
        }
        sb[i] = b;
        sa7[i] = 0.7f * ((b.z - b.x + 1.0f) * (b.w - b.y + 1.0f));
    }
    __syncthreads();
    const double* base64 = boxes + (size_t)img * PRE * 4;
    int wgid = blockIdx.x * 4 + wave;          // 0..251
    for (int half = 0; half < 2; ++half) {
        if (wgid >= QWAVES) break;
        int q = (half == 0) ? wgid : (NQUAD - 1 - wgid);
        int r0 = q * 4;
        float4 P0 = sb[r0], P1 = sb[r0 + 1], P2 = sb[r0 + 2], P3 = sb[r0 + 3];
        float A0 = sa7[r0], A1 = sa7[r0 + 1], A2 = sa7[r0 + 2], A3 = sa7[r0 + 3];
        int kmin = q >> 4;                      // == (4q)>>6, same for all 4 rows
        unsigned w0 = 0, w1 = 0, w2 = 0, w3 = 0;
        bool n0 = false, n1 = false, n2 = false, n3 = false;
        for (int k = kmin; k < 32; ++k) {
            int col = 64 * k + t;
            float4 Q = sb[col];
            float Ac = sa7[col];
            ROWOP(P0, A0, w0, n0)
            ROWOP(P1, A1, w1, n1)
            ROWOP(P2, A2, w2, n2)
            ROWOP(P3, A3, w3, n3)
        }
        if (__any(n0)) w0 = fixup_row(base64, sb, sa7, r0 + 0, t, kmin, P0, A0);
        if (__any(n1)) w1 = fixup_row(base64, sb, sa7, r0 + 1, t, kmin, P1, A1);
        if (__any(n2)) w2 = fixup_row(base64, sb, sa7, r0 + 2, t, kmin, P2, A2);
        if (__any(n3)) w3 = fixup_row(base64, sb, sa7, r0 + 3, t, kmin, P3, A3);
        mask[((size_t)img * MROWS + r0 + 0) * 64 + t] = w0;
        mask[((size_t)img * MROWS + r0 + 1) * 64 + t] = w1;
        mask[((size_t)img * MROWS + r0 + 2) * 64 + t] = w2;
        mask[((size_t)img * MROWS + r0 + 3) * 64 + t] = w3;
    }
}

// K9: sequential-scan greedy NMS, branchless scalar-mirror inner loop.
#define NMS_LOAD(B, G)                                          \
    _Pragma("unroll")                                           \
    for (int s = 0; s < 16; ++s) B[s] = mrow[((G) * 16 + s) * 64];

#define NMS_PROC(B, G, PAR) {                                   \
    int W = (G) >> 1;                                           \
    if ((PAR) == 0) s_cur = (unsigned)__builtin_amdgcn_readlane((int)sup, W); \
    _Pragma("unroll")                                           \
    for (int s = 0; s < 16; ++s) {                              \
        unsigned rb = (unsigned)__builtin_amdgcn_readlane((int)B[s], W); \
        unsigned bit = (s_cur >> (((PAR) << 4) + s)) & 1u;      \
        unsigned am = bit - 1u;  /* alive: ~0, dead: 0 */       \
        s_cur |= rb & am;                                       \
        s_pick |= am & (1u << (((PAR) << 4) + s));              \
        sup |= B[s] & am;                                       \
    }                                                           \
    if ((PAR) == 1) {                                           \
        pickedv = (t == W) ? (int)s_pick : pickedv;             \
        np += __builtin_popcount(s_pick);                       \
        s_pick = 0;                                             \
    }                                                           \
}

__global__ void __launch_bounds__(64) k_nms(const double* __restrict__ boxes,
                                            const float* __restrict__ scores,
                                            const unsigned* __restrict__ negmask,
                                            const unsigned* __restrict__ mask,
                                            float* __restrict__ out) {
    __shared__ int picks[POST];
    __shared__ unsigned wcnt[64];
    __shared__ int tot;
    int img = blockIdx.x;
    int t = threadIdx.x;
    unsigned sup = negmask[img * 64 + t];
    if (t == 62) sup |= 0xFFFF0000u;  // indices 2000..2015 invalid
    if (t == 63) sup = 0xFFFFFFFFu;   // indices 2016..2047 invalid
    const unsigned* mrow = mask + (size_t)img * MROWS * 64 + t;
    unsigned b0[16], b1[16], b2[16], b3[16];
    NMS_LOAD(b0, 0)
    NMS_LOAD(b1, 1)
    NMS_LOAD(b2, 2)
    NMS_LOAD(b3, 3)
    int np = 0;
    unsigned s_cur = 0, s_pick = 0;
    int pickedv = 0;
    // 125 groups of 16 rows (2000). Main loop: groups 0..123; epilogue: 124.
    for (int gg = 0; gg < 124; gg += 4) {
        NMS_PROC(b0, gg + 0, 0) NMS_LOAD(b0, gg + 4)
        NMS_PROC(b1, gg + 1, 1) NMS_LOAD(b1, gg + 5)
        NMS_PROC(b2, gg + 2, 0) NMS_LOAD(b2, gg + 6)
        NMS_PROC(b3, gg + 3, 1) NMS_LOAD(b3, gg + 7)   // max load group 127 < MROWS/16
        if (np >= POST) break;
    }
    if (np < POST) {
        NMS_PROC(b0, 124, 0)   // jj 1984..1999, word 62 low half
        pickedv = (t == 62) ? (int)s_pick : pickedv;
        np += __builtin_popcount(s_pick);
    }
    // epilogue: materialize picks[] from the bitmap (lane W holds word W)
    wcnt[t] = (unsigned)__builtin_popcount((unsigned)pickedv);
    __syncthreads();
    int pre = 0;
    for (int i = 0; i < t; ++i) pre += (int)wcnt[i];
    if (t == 63) tot = pre + (int)wcnt[63];
    __syncthreads();
    unsigned pw = (unsigned)pickedv;
    int rank = pre;
    while (pw) {
        int b = __ffs(pw) - 1;
        pw &= pw - 1;
        if (rank < POST) picks[rank] = t * 32 + b;
        rank++;
    }
    __syncthreads();
    int np_final = tot > POST ? POST : tot;
    float* ob = out + (size_t)img * POST * 4;
    float* os = out + (size_t)NIMG * POST * 4 + (size_t)img * POST;
    for (int k = t; k < POST; k += 64) {
        if (k < np_final) {
            int p = picks[k];
            const double* bp = boxes + ((size_t)img * PRE + p) * 4;
            ob[k * 4 + 0] = (float)bp[0];
            ob[k * 4 + 1] = (float)bp[1];
            ob[k * 4 + 2] = (float)bp[2];
            ob[k * 4 + 3] = (float)bp[3];
            os[k] = scores[img * PRE + p];
        } else {
            ob[k * 4 + 0] = 0.0f; ob[k * 4 + 1] = 0.0f;
            ob[k * 4 + 2] = 0.0f; ob[k * 4 + 3] = 0.0f;
            os[k] = NEGF;
        }
    }
}

extern "C" void kernel_launch(void* const* d_in, const int* in_sizes, int n_in,
                              void* d_out, int out_size, void* d_ws, size_t ws_size,
                              hipStream_t stream) {
    const float* anchors = (const float*)d_in[0];
    const float4* obj4 = (const float4*)d_in[1];
    const float* br = (const float*)d_in[2];
    float* out = (float*)d_out;

    char* ws = (char*)d_ws;
    size_t off = 0;
    auto alloc = [&](size_t bytes) {
        void* p = ws + off;
        off = (off + bytes + 255) & ~(size_t)255;
        return p;
    };
    // zero-initialized region (single fused memset): hist..negmask
    unsigned* hist = (unsigned*)alloc((size_t)NIMG * NBUCKET * 4);
    unsigned* hist2 = (unsigned*)alloc((size_t)NIMG * NBUCKET * 4);
    unsigned* bsel = (unsigned*)alloc(NIMG * 4);
    unsigned* cntAbove = (unsigned*)alloc(NIMG * 4);
    unsigned* thr32 = (unsigned*)alloc(NIMG * 4);
    unsigned* selcnt = (unsigned*)alloc((size_t)NIMG * 64 * 4);      // one cache line per image
    unsigned* negmask = (unsigned*)alloc((size_t)NIMG * 64 * 4);
    size_t zero_bytes = off;
    // non-zeroed buffers
    unsigned long long* keys = (unsigned long long*)alloc((size_t)NIMG * CAP2 * 8);
    double* boxes = (double*)alloc((size_t)NIMG * PRE * 4 * 8);
    float4* boxesf = (float4*)alloc((size_t)NIMG * PRE * 16);
    float* scores = (float*)alloc((size_t)NIMG * PRE * 4);
    unsigned* mask = (unsigned*)alloc((size_t)NIMG * MROWS * 64 * 4);

    hipMemsetAsync(hist, 0, zero_bytes, stream);

    k_hist<<<dim3(64, NIMG), 256, 0, stream>>>(obj4, hist);
    k_thresh<<<NIMG, 256, 0, stream>>>(hist, bsel, cntAbove);
    k_hist2<<<dim3(64, NIMG), 256, 0, stream>>>(obj4, bsel, hist2);
    k_thresh2<<<NIMG, 256, 0, stream>>>(hist2, bsel, cntAbove, thr32);
    k_compact<<<dim3(64, NIMG), 256, 0, stream>>>(obj4, thr32, selcnt, keys);
    k_sort<<<NIMG, 1024, 0, stream>>>(keys, selcnt);
    k_decode<<<(NIMG * PRE + 255) / 256, 256, 0, stream>>>(anchors, br, keys, boxes, boxesf, scores, negmask);
    k_mask<<<dim3((QWAVES + 3) / 4, NIMG), 256, 0, stream>>>(boxesf, boxes, mask);
    k_nms<<<NIMG, 64, 0, stream>>>(boxes, scores, negmask, mask, out);
}

// Round 15
// 143.240 us; speedup vs baseline: 2.1441x; 1.0209x over previous
//
#include <hip/hip_runtime.h>
#include <math.h>

#define NIMG 16
#define A 3
#define HW 65536
#define AHW 196608
#define PRE 2000
#define POST 1000
#define CAP2 2048
#define MROWS 2048
#define NBUCKET 2048
#define NEGF (-1e30f)
#define LBUF 256
#define BW 0.01f
#define BD 4.0f
#define NQUAD 500      // 2000 rows / 4

__device__ __forceinline__ unsigned mapf(float x) {
    unsigned u = __float_as_uint(x);
    return (u & 0x80000000u) ? ~u : (u | 0x80000000u);
}

// K1: per-image histogram of top 11 bits of monotone-mapped objectness (float4 loads)
__global__ void __launch_bounds__(256) k_hist(const float4* __restrict__ obj4,
                                              unsigned* __restrict__ hist) {
    __shared__ unsigned lh[NBUCKET];
    int img = blockIdx.y;
    for (int i = threadIdx.x; i < NBUCKET; i += 256) lh[i] = 0;
    __syncthreads();
    const float4* p = obj4 + (size_t)img * (AHW / 4);
    int stride = gridDim.x * 256;
    for (int v = blockIdx.x * 256 + threadIdx.x; v < AHW / 4; v += stride) {
        float4 f = p[v];
        atomicAdd(&lh[mapf(f.x) >> 21], 1u);
        atomicAdd(&lh[mapf(f.y) >> 21], 1u);
        atomicAdd(&lh[mapf(f.z) >> 21], 1u);
        atomicAdd(&lh[mapf(f.w) >> 21], 1u);
    }
    __syncthreads();
    unsigned* gh = hist + img * NBUCKET;
    for (int i = threadIdx.x; i < NBUCKET; i += 256)
        if (lh[i]) atomicAdd(&gh[i], lh[i]);
}

// Parallel threshold scan: suffix-sum over 256 coarse chunks (Hillis-Steele),
// unique crossing thread does the <=8-bucket descent.
__device__ __forceinline__ void thresh_scan_par(const unsigned* __restrict__ gh,
                                                unsigned cum0,
                                                unsigned* part, unsigned* sfx,
                                                unsigned* outB, unsigned* outCum) {
    int t = threadIdx.x;
    unsigned s = 0;
    for (int k = 0; k < 8; ++k) s += gh[t * 8 + k];
    part[t] = s;
    sfx[t] = s;
    __syncthreads();
    for (int d = 1; d < 256; d <<= 1) {
        unsigned v = (t + d < 256) ? sfx[t + d] : 0u;
        __syncthreads();
        sfx[t] += v;
        __syncthreads();
    }
    unsigned inc = sfx[t], exc = inc - part[t];
    if (cum0 + inc >= PRE && cum0 + exc < PRE) {   // exactly one thread
        unsigned cum = cum0 + exc;
        for (int i = t * 8 + 7; i >= t * 8; --i) {
            unsigned h = gh[i];
            if (cum + h >= PRE) { *outB = (unsigned)i; *outCum = cum; break; }
            cum += h;
        }
    }
}

// K2: coarse threshold bucket B per image + count strictly above B
__global__ void __launch_bounds__(256) k_thresh(const unsigned* __restrict__ hist,
                                                unsigned* __restrict__ bsel,
                                                unsigned* __restrict__ cntAbove) {
    __shared__ unsigned part[256], sfx[256];
    int img = blockIdx.x;
    thresh_scan_par(hist + img * NBUCKET, 0u, part, sfx, &bsel[img], &cntAbove[img]);
}

// K3: histogram of next 11 bits within coarse bucket B (float4 loads)
__global__ void __launch_bounds__(256) k_hist2(const float4* __restrict__ obj4,
                                               const unsigned* __restrict__ bsel,
                                               unsigned* __restrict__ hist2) {
    __shared__ unsigned lh[NBUCKET];
    int img = blockIdx.y;
    unsigned B = bsel[img];
    for (int i = threadIdx.x; i < NBUCKET; i += 256) lh[i] = 0;
    __syncthreads();
    const float4* p = obj4 + (size_t)img * (AHW / 4);
    int stride = gridDim.x * 256;
    for (int v = blockIdx.x * 256 + threadIdx.x; v < AHW / 4; v += stride) {
        float4 f = p[v];
        unsigned m0 = mapf(f.x), m1 = mapf(f.y), m2 = mapf(f.z), m3 = mapf(f.w);
        if ((m0 >> 21) == B) atomicAdd(&lh[(m0 >> 10) & 0x7FF], 1u);
        if ((m1 >> 21) == B) atomicAdd(&lh[(m1 >> 10) & 0x7FF], 1u);
        if ((m2 >> 21) == B) atomicAdd(&lh[(m2 >> 10) & 0x7FF], 1u);
        if ((m3 >> 21) == B) atomicAdd(&lh[(m3 >> 10) & 0x7FF], 1u);
    }
    __syncthreads();
    unsigned* gh = hist2 + img * NBUCKET;
    for (int i = threadIdx.x; i < NBUCKET; i += 256)
        if (lh[i]) atomicAdd(&gh[i], lh[i]);
}

// K4: refine to 22-bit threshold
__global__ void __launch_bounds__(256) k_thresh2(const unsigned* __restrict__ hist2,
                                                 const unsigned* __restrict__ bsel,
                                                 const unsigned* __restrict__ cntAbove,
                                                 unsigned* __restrict__ thr32) {
    __shared__ unsigned part[256], sfx[256];
    __shared__ unsigned bk, cumdummy;
    int img = blockIdx.x;
    thresh_scan_par(hist2 + img * NBUCKET, cntAbove[img], part, sfx, &bk, &cumdummy);
    __syncthreads();
    if (threadIdx.x == 0) thr32[img] = (bsel[img] << 21) | (bk << 10);
}

// K5: compact candidates with m >= thr. Two-level: LDS staging + one global
// atomic per block (selcnt padded to a private cache line per image).
__global__ void __launch_bounds__(256) k_compact(const float4* __restrict__ obj4,
                                                 const unsigned* __restrict__ thr32,
                                                 unsigned* __restrict__ selcnt,
                                                 unsigned long long* __restrict__ keys) {
    __shared__ unsigned long long lbuf[LBUF];
    __shared__ unsigned lcnt, gbase;
    int img = blockIdx.y;
    unsigned thr = thr32[img];
    if (threadIdx.x == 0) lcnt = 0;
    __syncthreads();
    const float4* p = obj4 + (size_t)img * (AHW / 4);
    int v0 = blockIdx.x * 768;
    #pragma unroll
    for (int it = 0; it < 3; ++it) {
        int v = v0 + it * 256 + threadIdx.x;
        float4 f = p[v];
        int jb = v * 4;
        #pragma unroll
        for (int k = 0; k < 4; ++k) {
            float x = k == 0 ? f.x : (k == 1 ? f.y : (k == 2 ? f.z : f.w));
            unsigned m = mapf(x);
            if (m >= thr) {
                int j = jb + k;
                int a = j >> 16;
                int hw = j & 65535;
                unsigned idx = (unsigned)(hw * A + a);
                unsigned pos = atomicAdd(&lcnt, 1u);
                if (pos < LBUF)
                    lbuf[pos] = ((unsigned long long)m << 32) | (unsigned)(~idx);
            }
        }
    }
    __syncthreads();
    unsigned n = lcnt > LBUF ? LBUF : lcnt;
    if (threadIdx.x == 0) gbase = atomicAdd(&selcnt[img * 64], n);
    __syncthreads();
    if (threadIdx.x < n) {
        unsigned pos = gbase + threadIdx.x;
        if (pos < CAP2)
            keys[(size_t)img * CAP2 + pos] = lbuf[threadIdx.x];
    }
}

// K6: per-image bitonic sort, descending. Tail beyond the valid count is
// padded with 0 keys in LDS (keys buffer itself is not zeroed).
__global__ void __launch_bounds__(1024) k_sort(unsigned long long* __restrict__ keys,
                                               const unsigned* __restrict__ selcnt) {
    __shared__ unsigned long long s[CAP2];
    int img = blockIdx.x;
    unsigned cnt = selcnt[img * 64];
    if (cnt > CAP2) cnt = CAP2;
    unsigned long long* g = keys + (size_t)img * CAP2;
    for (int i = threadIdx.x; i < CAP2; i += 1024)
        s[i] = (i < (int)cnt) ? g[i] : 0ULL;
    __syncthreads();
    for (int k2 = 2; k2 <= CAP2; k2 <<= 1) {
        for (int j = k2 >> 1; j > 0; j >>= 1) {
            for (int i = threadIdx.x; i < CAP2; i += 1024) {
                int ixj = i ^ j;
                if (ixj > i) {
                    unsigned long long a = s[i], b = s[ixj];
                    bool up = ((i & k2) == 0);
                    if (up ? (a < b) : (a > b)) { s[i] = b; s[ixj] = a; }
                }
            }
            __syncthreads();
        }
    }
    for (int i = threadIdx.x; i < PRE; i += 1024) g[i] = s[i];
}

// K7: decode boxes (f64), clip, MIN_SIZE filter, sigmoid score.
// boxesf is PADDED to MROWS with sentinel boxes (never overlap) so k_mask
// needs no column clamp.
__global__ void k_decode(const float* __restrict__ anchors, const float* __restrict__ br,
                         const unsigned long long* __restrict__ keys,
                         double* __restrict__ boxes, float4* __restrict__ boxesf,
                         float* __restrict__ scores, unsigned* __restrict__ negmask) {
    int g = blockIdx.x * blockDim.x + threadIdx.x;
    if (g >= NIMG * MROWS) return;
    int img = g >> 11, r = g & (MROWS - 1);
    float4* bfp = boxesf + (size_t)img * MROWS + r;
    if (r >= PRE) {
        float4 bf;
        bf.x = 1e8f; bf.y = 1e8f; bf.z = -1e8f; bf.w = -1e8f;
        *bfp = bf;
        return;
    }
    unsigned long long key = keys[(size_t)img * CAP2 + r];
    unsigned m = (unsigned)(key >> 32);
    unsigned idx = ~(unsigned)key;
    unsigned u = (m & 0x80000000u) ? (m ^ 0x80000000u) : ~m;
    float x = __uint_as_float(u);
    double sc = 1.0 / (1.0 + exp(-(double)x));
    int a = idx % 3;
    int hw = idx / 3;
    const float* anc = anchors + ((size_t)img * AHW + idx) * 4;
    double ax1 = anc[0], ay1 = anc[1], ax2 = anc[2], ay2 = anc[3];
    double aw = ax2 - ax1 + 1.0, ah = ay2 - ay1 + 1.0;
    double cx = ax1 + 0.5 * aw, cy = ay1 + 0.5 * ah;
    const float* bp = br + (size_t)img * 12 * HW + (size_t)a * 4 * HW + hw;
    double dx = bp[0];
    double dy = bp[(size_t)HW];
    double dw = bp[(size_t)2 * HW];
    double dh = bp[(size_t)3 * HW];
    const double CLIPV = 4.135166556742356; // log(1000/16)
    dw = fmin(dw, CLIPV); dh = fmin(dh, CLIPV);
    double pcx = dx * aw + cx, pcy = dy * ah + cy;
    double pw = exp(dw) * aw, ph = exp(dh) * ah;
    double x1 = pcx - 0.5 * pw, y1 = pcy - 0.5 * ph;
    double x2 = pcx + 0.5 * pw - 1.0, y2 = pcy + 0.5 * ph - 1.0;
    x1 = fmin(fmax(x1, 0.0), 1023.0);
    y1 = fmin(fmax(y1, 0.0), 1023.0);
    x2 = fmin(fmax(x2, 0.0), 1023.0);
    y2 = fmin(fmax(y2, 0.0), 1023.0);
    bool keep = (x2 - x1 + 1.0 >= 0.0) && (y2 - y1 + 1.0 >= 0.0);
    double* bo = boxes + ((size_t)img * PRE + r) * 4;
    bo[0] = x1; bo[1] = y1; bo[2] = x2; bo[3] = y2;
    float4 bf;
    bf.x = (float)x1; bf.y = (float)y1; bf.z = (float)x2; bf.w = (float)y2;
    *bfp = bf;
    scores[img * PRE + r] = keep ? (float)sc : NEGF;
    if (!keep) atomicOr(&negmask[img * 64 + (r >> 5)], 1u << (r & 31));
}

// exact f64 rebuild of one mask row's parity-k words (rare path)
__device__ __noinline__ unsigned fixup_row(const double* __restrict__ base64,
                                           const float4* __restrict__ fb,
                                           int r, int t, int k0,
                                           float4 P, float Arow) {
    const double* ri = base64 + (size_t)r * 4;
    double X1 = ri[0], Y1 = ri[1], X2 = ri[2], Y2 = ri[3];
    double AR = (X2 - X1 + 1.0) * (Y2 - Y1 + 1.0);
    unsigned myw = 0;
    for (int k = k0; k < 32; k += 2) {
        int col = 64 * k + t;
        float4 q = fb[col];
        float Ac = 0.7f * ((q.z - q.x + 1.0f) * (q.w - q.y + 1.0f));
        float iw = fminf(P.z, q.z) - fmaxf(P.x, q.x) + 1.0f;
        float ih = fminf(P.w, q.w) - fmaxf(P.y, q.y) + 1.0f;
        float inter = iw * ih;
        float d = fmaf(1.7f, inter, -(Arow + Ac));
        bool ov = (iw > -BW) & (ih > -BW);
        bool need = ov & ((iw < BW) | (ih < BW) | (fabsf(d) < BD));
        bool res = ov & (d > 0.0f);
        if (need) {   // col < PRE guaranteed (sentinels can't set need)
            const double* rj = base64 + (size_t)col * 4;
            double bX1 = rj[0], bY1 = rj[1], bX2 = rj[2], bY2 = rj[3];
            double IW = fmin(X2, bX2) - fmax(X1, bX1) + 1.0;
            double IH = fmin(Y2, bY2) - fmax(Y1, bY1) + 1.0;
            IW = IW > 0.0 ? IW : 0.0;
            IH = IH > 0.0 ? IH : 0.0;
            double INTER = IW * IH;
            double AJ = (bX2 - bX1 + 1.0) * (bY2 - bY1 + 1.0);
            double IOU = INTER / ((AR + AJ) - INTER);
            res = IOU > 0.7;
        }
        unsigned long long bb = __ballot(res);
        myw = (t == 2 * k) ? (unsigned)bb : myw;
        myw = (t == 2 * k + 1) ? (unsigned)(bb >> 32) : myw;
    }
    return myw;
}

// K8: upper-triangle IoU suppression bitmask. NO LDS: boxesf (32KB/img) is
// L1/L2-resident; column loads are coalesced 1KB/wave. Each (quad-pair,
// k-parity) is one wave -> 500 waves/img, 2000 blocks, ~8 waves/SIMD.
// Predicated stores per parity; below-diagonal words are never written
// (provably never read ahead of the scan head in k_nms). Also emits
// diag[r] = mask[r][r>>5] (self-word) for k_nms's scalar chain.
#define ROWOP(P, Arow, wreg, nflag)                                \
    {                                                              \
        float iw = fminf(P.z, Q.z) - fmaxf(P.x, Q.x) + 1.0f;       \
        float ih = fminf(P.w, Q.w) - fmaxf(P.y, Q.y) + 1.0f;       \
        float inter = iw * ih;                                     \
        float d = fmaf(1.7f, inter, -(Arow + Ac));                 \
        bool ov = (iw > -BW) & (ih > -BW);                         \
        nflag |= ov & ((iw < BW) | (ih < BW) | (fabsf(d) < BD));   \
        bool res = ov & (d > 0.0f);                                \
        unsigned long long bb = __ballot(res);                     \
        wreg = (t == 2 * k) ? (unsigned)bb : wreg;                 \
        wreg = (t == 2 * k + 1) ? (unsigned)(bb >> 32) : wreg;     \
    }

__global__ void __launch_bounds__(256) k_mask(const float4* __restrict__ boxesf,
                                              const double* __restrict__ boxes,
                                              unsigned* __restrict__ mask,
                                              unsigned* __restrict__ diag) {
    int img = blockIdx.y;
    int tid = threadIdx.x;
    int wave = tid >> 6, t = tid & 63;
    int wgid = blockIdx.x * 4 + wave;       // 0..499
    int pairIdx = wgid >> 1;                // 0..249
    int khalf = wgid & 1;
    const float4* fb = boxesf + (size_t)img * MROWS;
    const double* base64 = boxes + (size_t)img * PRE * 4;
    int tw = t >> 1;
    for (int half = 0; half < 2; ++half) {
        int q = (half == 0) ? pairIdx : (NQUAD - 1 - pairIdx);
        int r0 = q * 4;
        float4 P0 = fb[r0], P1 = fb[r0 + 1], P2 = fb[r0 + 2], P3 = fb[r0 + 3];
        float A0 = 0.7f * ((P0.z - P0.x + 1.0f) * (P0.w - P0.y + 1.0f));
        float A1 = 0.7f * ((P1.z - P1.x + 1.0f) * (P1.w - P1.y + 1.0f));
        float A2 = 0.7f * ((P2.z - P2.x + 1.0f) * (P2.w - P2.y + 1.0f));
        float A3 = 0.7f * ((P3.z - P3.x + 1.0f) * (P3.w - P3.y + 1.0f));
        int kmin = q >> 4;
        int k0 = kmin + ((khalf ^ (kmin & 1)) & 1);   // first k with (k&1)==khalf
        unsigned w0 = 0, w1 = 0, w2 = 0, w3 = 0;
        bool n0 = false, n1 = false, n2 = false, n3 = false;
        for (int k = k0; k < 32; k += 2) {
            int col = 64 * k + t;
            float4 Q = fb[col];
            float Ac = 0.7f * ((Q.z - Q.x + 1.0f) * (Q.w - Q.y + 1.0f));
            ROWOP(P0, A0, w0, n0)
            ROWOP(P1, A1, w1, n1)
            ROWOP(P2, A2, w2, n2)
            ROWOP(P3, A3, w3, n3)
        }
        if (__any(n0)) w0 = fixup_row(base64, fb, r0 + 0, t, k0, P0, A0);
        if (__any(n1)) w1 = fixup_row(base64, fb, r0 + 1, t, k0, P1, A1);
        if (__any(n2)) w2 = fixup_row(base64, fb, r0 + 2, t, k0, P2, A2);
        if (__any(n3)) w3 = fixup_row(base64, fb, r0 + 3, t, k0, P3, A3);
        size_t rowb = (size_t)img * MROWS + r0;
        bool own = (tw >= kmin) && ((tw & 1) == khalf);
        if (own) {
            mask[(rowb + 0) * 64 + t] = w0;
            mask[(rowb + 1) * 64 + t] = w1;
            mask[(rowb + 2) * 64 + t] = w2;
            mask[(rowb + 3) * 64 + t] = w3;
        }
        if (((kmin & 1) == khalf) && (t == (q >> 3))) {   // self-word lane
            diag[rowb + 0] = w0;
            diag[rowb + 1] = w1;
            diag[rowb + 2] = w2;
            diag[rowb + 3] = w3;
        }
    }
}

// K9: sequential-scan greedy NMS. Inner chain is pure SALU: the row's
// self-word comes from diag[] via uniform-address scalar loads (contiguous
// 16-dword groups -> s_load), eliminating the v_readlane VALU->SALU hazard.
#define NMS_LOAD(B, G)                                          \
    _Pragma("unroll")                                           \
    for (int s = 0; s < 16; ++s) B[s] = mrow[((G) * 16 + s) * 64];

#define NMS_PROC(B, G, PAR) {                                   \
    int W = (G) >> 1;                                           \
    if ((PAR) == 0) s_cur = (unsigned)__builtin_amdgcn_readlane((int)sup, W); \
    _Pragma("unroll")                                           \
    for (int s = 0; s < 16; ++s) {                              \
        unsigned rb = dg[(G) * 16 + s];   /* uniform -> s_load */ \
        unsigned sh = ((PAR) << 4) + s;                         \
        unsigned bit = (s_cur >> sh) & 1u;                      \
        unsigned am = bit - 1u;  /* alive: ~0, dead: 0 */       \
        s_cur |= rb & am;                                       \
        s_pick |= am & (1u << sh);                              \
        sup |= B[s] & am;                                       \
    }                                                           \
    if ((PAR) == 1) {                                           \
        pickedv = (t == W) ? (int)s_pick : pickedv;             \
        np += __builtin_popcount(s_pick);                       \
        s_pick = 0;                                             \
    }                                                           \
}

__global__ void __launch_bounds__(64) k_nms(const double* __restrict__ boxes,
                                            const float* __restrict__ scores,
                                            const unsigned* __restrict__ negmask,
                                            const unsigned* __restrict__ mask,
                                            const unsigned* __restrict__ diag,
                                            float* __restrict__ out) {
    __shared__ int picks[POST];
    __shared__ unsigned wcnt[64];
    __shared__ int tot;
    int img = blockIdx.x;
    int t = threadIdx.x;
    unsigned sup = negmask[img * 64 + t];
    if (t == 62) sup |= 0xFFFF0000u;  // indices 2000..2015 invalid
    if (t == 63) sup = 0xFFFFFFFFu;   // indices 2016..2047 invalid
    const unsigned* mrow = mask + (size_t)img * MROWS * 64 + t;
    const unsigned* dg = diag + (size_t)img * MROWS;
    unsigned b0[16], b1[16], b2[16], b3[16];
    NMS_LOAD(b0, 0)
    NMS_LOAD(b1, 1)
    NMS_LOAD(b2, 2)
    NMS_LOAD(b3, 3)
    int np = 0;
    unsigned s_cur = 0, s_pick = 0;
    int pickedv = 0;
    // 125 groups of 16 rows (2000). Main loop: groups 0..123; epilogue: 124.
    for (int gg = 0; gg < 124; gg += 4) {
        NMS_PROC(b0, gg + 0, 0) NMS_LOAD(b0, gg + 4)
        NMS_PROC(b1, gg + 1, 1) NMS_LOAD(b1, gg + 5)
        NMS_PROC(b2, gg + 2, 0) NMS_LOAD(b2, gg + 6)
        NMS_PROC(b3, gg + 3, 1) NMS_LOAD(b3, gg + 7)   // max load group 127 < MROWS/16
        if (np >= POST) break;
    }
    if (np < POST) {
        NMS_PROC(b0, 124, 0)   // jj 1984..1999, word 62 low half
        pickedv = (t == 62) ? (int)s_pick : pickedv;
        np += __builtin_popcount(s_pick);
    }
    // epilogue: materialize picks[] from the bitmap (lane W holds word W)
    wcnt[t] = (unsigned)__builtin_popcount((unsigned)pickedv);
    __syncthreads();
    int pre = 0;
    for (int i = 0; i < t; ++i) pre += (int)wcnt[i];
    if (t == 63) tot = pre + (int)wcnt[63];
    __syncthreads();
    unsigned pw = (unsigned)pickedv;
    int rank = pre;
    while (pw) {
        int b = __ffs(pw) - 1;
        pw &= pw - 1;
        if (rank < POST) picks[rank] = t * 32 + b;
        rank++;
    }
    __syncthreads();
    int np_final = tot > POST ? POST : tot;
    float* ob = out + (size_t)img * POST * 4;
    float* os = out + (size_t)NIMG * POST * 4 + (size_t)img * POST;
    for (int k = t; k < POST; k += 64) {
        if (k < np_final) {
            int p = picks[k];
            const double* bp = boxes + ((size_t)img * PRE + p) * 4;
            ob[k * 4 + 0] = (float)bp[0];
            ob[k * 4 + 1] = (float)bp[1];
            ob[k * 4 + 2] = (float)bp[2];
            ob[k * 4 + 3] = (float)bp[3];
            os[k] = scores[img * PRE + p];
        } else {
            ob[k * 4 + 0] = 0.0f; ob[k * 4 + 1] = 0.0f;
            ob[k * 4 + 2] = 0.0f; ob[k * 4 + 3] = 0.0f;
            os[k] = NEGF;
        }
    }
}

extern "C" void kernel_launch(void* const* d_in, const int* in_sizes, int n_in,
                              void* d_out, int out_size, void* d_ws, size_t ws_size,
                              hipStream_t stream) {
    const float* anchors = (const float*)d_in[0];
    const float4* obj4 = (const float4*)d_in[1];
    const float* br = (const float*)d_in[2];
    float* out = (float*)d_out;

    char* ws = (char*)d_ws;
    size_t off = 0;
    auto alloc = [&](size_t bytes) {
        void* p = ws + off;
        off = (off + bytes + 255) & ~(size_t)255;
        return p;
    };
    // zero-initialized region (single fused memset): hist..negmask
    unsigned* hist = (unsigned*)alloc((size_t)NIMG * NBUCKET * 4);
    unsigned* hist2 = (unsigned*)alloc((size_t)NIMG * NBUCKET * 4);
    unsigned* bsel = (unsigned*)alloc(NIMG * 4);
    unsigned* cntAbove = (unsigned*)alloc(NIMG * 4);
    unsigned* thr32 = (unsigned*)alloc(NIMG * 4);
    unsigned* selcnt = (unsigned*)alloc((size_t)NIMG * 64 * 4);      // one cache line per image
    unsigned* negmask = (unsigned*)alloc((size_t)NIMG * 64 * 4);
    size_t zero_bytes = off;
    // non-zeroed buffers
    unsigned long long* keys = (unsigned long long*)alloc((size_t)NIMG * CAP2 * 8);
    double* boxes = (double*)alloc((size_t)NIMG * PRE * 4 * 8);
    float4* boxesf = (float4*)alloc((size_t)NIMG * MROWS * 16);
    float* scores = (float*)alloc((size_t)NIMG * PRE * 4);
    unsigned* mask = (unsigned*)alloc((size_t)NIMG * MROWS * 64 * 4);
    unsigned* diag = (unsigned*)alloc((size_t)NIMG * MROWS * 4);

    hipMemsetAsync(hist, 0, zero_bytes, stream);

    k_hist<<<dim3(64, NIMG), 256, 0, stream>>>(obj4, hist);
    k_thresh<<<NIMG, 256, 0, stream>>>(hist, bsel, cntAbove);
    k_hist2<<<dim3(64, NIMG), 256, 0, stream>>>(obj4, bsel, hist2);
    k_thresh2<<<NIMG, 256, 0, stream>>>(hist2, bsel, cntAbove, thr32);
    k_compact<<<dim3(64, NIMG), 256, 0, stream>>>(obj4, thr32, selcnt, keys);
    k_sort<<<NIMG, 1024, 0, stream>>>(keys, selcnt);
    k_decode<<<(NIMG * MROWS + 255) / 256, 256, 0, stream>>>(anchors, br, keys, boxes, boxesf, scores, negmask);
    k_mask<<<dim3(125, NIMG), 256, 0, stream>>>(boxesf, boxes, mask, diag);
    k_nms<<<NIMG, 64, 0, stream>>>(boxes, scores, negmask, mask, diag, out);
}

// Round 16
// 137.010 us; speedup vs baseline: 2.2416x; 1.0455x over previous
//
#include <hip/hip_runtime.h>
#include <math.h>

#define NIMG 16
#define A 3
#define HW 65536
#define AHW 196608
#define PRE 2000
#define POST 1000
#define CAP2 2048
#define MROWS 2048
#define NBUCKET 2048
#define NEGF (-1e30f)
#define LBUF 256
#define BW 0.01f
#define BD 4.0f
#define NQUAD 500      // 2000 rows / 4

__device__ __forceinline__ unsigned mapf(float x) {
    unsigned u = __float_as_uint(x);
    return (u & 0x80000000u) ? ~u : (u | 0x80000000u);
}

// K1: per-image histogram of top 11 bits of monotone-mapped objectness (float4 loads)
__global__ void __launch_bounds__(256) k_hist(const float4* __restrict__ obj4,
                                              unsigned* __restrict__ hist) {
    __shared__ unsigned lh[NBUCKET];
    int img = blockIdx.y;
    for (int i = threadIdx.x; i < NBUCKET; i += 256) lh[i] = 0;
    __syncthreads();
    const float4* p = obj4 + (size_t)img * (AHW / 4);
    int stride = gridDim.x * 256;
    for (int v = blockIdx.x * 256 + threadIdx.x; v < AHW / 4; v += stride) {
        float4 f = p[v];
        atomicAdd(&lh[mapf(f.x) >> 21], 1u);
        atomicAdd(&lh[mapf(f.y) >> 21], 1u);
        atomicAdd(&lh[mapf(f.z) >> 21], 1u);
        atomicAdd(&lh[mapf(f.w) >> 21], 1u);
    }
    __syncthreads();
    unsigned* gh = hist + img * NBUCKET;
    for (int i = threadIdx.x; i < NBUCKET; i += 256)
        if (lh[i]) atomicAdd(&gh[i], lh[i]);
}

// Parallel threshold scan: suffix-sum over 256 coarse chunks (Hillis-Steele),
// unique crossing thread does the <=8-bucket descent.
__device__ __forceinline__ void thresh_scan_par(const unsigned* __restrict__ gh,
                                                unsigned cum0,
                                                unsigned* part, unsigned* sfx,
                                                unsigned* outB, unsigned* outCum) {
    int t = threadIdx.x;
    unsigned s = 0;
    for (int k = 0; k < 8; ++k) s += gh[t * 8 + k];
    part[t] = s;
    sfx[t] = s;
    __syncthreads();
    for (int d = 1; d < 256; d <<= 1) {
        unsigned v = (t + d < 256) ? sfx[t + d] : 0u;
        __syncthreads();
        sfx[t] += v;
        __syncthreads();
    }
    unsigned inc = sfx[t], exc = inc - part[t];
    if (cum0 + inc >= PRE && cum0 + exc < PRE) {   // exactly one thread
        unsigned cum = cum0 + exc;
        for (int i = t * 8 + 7; i >= t * 8; --i) {
            unsigned h = gh[i];
            if (cum + h >= PRE) { *outB = (unsigned)i; *outCum = cum; break; }
            cum += h;
        }
    }
}

// K2: coarse threshold bucket B per image + count strictly above B
__global__ void __launch_bounds__(256) k_thresh(const unsigned* __restrict__ hist,
                                                unsigned* __restrict__ bsel,
                                                unsigned* __restrict__ cntAbove) {
    __shared__ unsigned part[256], sfx[256];
    int img = blockIdx.x;
    thresh_scan_par(hist + img * NBUCKET, 0u, part, sfx, &bsel[img], &cntAbove[img]);
}

// K3: histogram of next 11 bits within coarse bucket B (float4 loads)
__global__ void __launch_bounds__(256) k_hist2(const float4* __restrict__ obj4,
                                               const unsigned* __restrict__ bsel,
                                               unsigned* __restrict__ hist2) {
    __shared__ unsigned lh[NBUCKET];
    int img = blockIdx.y;
    unsigned B = bsel[img];
    for (int i = threadIdx.x; i < NBUCKET; i += 256) lh[i] = 0;
    __syncthreads();
    const float4* p = obj4 + (size_t)img * (AHW / 4);
    int stride = gridDim.x * 256;
    for (int v = blockIdx.x * 256 + threadIdx.x; v < AHW / 4; v += stride) {
        float4 f = p[v];
        unsigned m0 = mapf(f.x), m1 = mapf(f.y), m2 = mapf(f.z), m3 = mapf(f.w);
        if ((m0 >> 21) == B) atomicAdd(&lh[(m0 >> 10) & 0x7FF], 1u);
        if ((m1 >> 21) == B) atomicAdd(&lh[(m1 >> 10) & 0x7FF], 1u);
        if ((m2 >> 21) == B) atomicAdd(&lh[(m2 >> 10) & 0x7FF], 1u);
        if ((m3 >> 21) == B) atomicAdd(&lh[(m3 >> 10) & 0x7FF], 1u);
    }
    __syncthreads();
    unsigned* gh = hist2 + img * NBUCKET;
    for (int i = threadIdx.x; i < NBUCKET; i += 256)
        if (lh[i]) atomicAdd(&gh[i], lh[i]);
}

// K4: refine to 22-bit threshold
__global__ void __launch_bounds__(256) k_thresh2(const unsigned* __restrict__ hist2,
                                                 const unsigned* __restrict__ bsel,
                                                 const unsigned* __restrict__ cntAbove,
                                                 unsigned* __restrict__ thr32) {
    __shared__ unsigned part[256], sfx[256];
    __shared__ unsigned bk, cumdummy;
    int img = blockIdx.x;
    thresh_scan_par(hist2 + img * NBUCKET, cntAbove[img], part, sfx, &bk, &cumdummy);
    __syncthreads();
    if (threadIdx.x == 0) thr32[img] = (bsel[img] << 21) | (bk << 10);
}

// K5: compact candidates with m >= thr. Two-level: LDS staging + one global
// atomic per block (selcnt padded to a private cache line per image).
__global__ void __launch_bounds__(256) k_compact(const float4* __restrict__ obj4,
                                                 const unsigned* __restrict__ thr32,
                                                 unsigned* __restrict__ selcnt,
                                                 unsigned long long* __restrict__ keys) {
    __shared__ unsigned long long lbuf[LBUF];
    __shared__ unsigned lcnt, gbase;
    int img = blockIdx.y;
    unsigned thr = thr32[img];
    if (threadIdx.x == 0) lcnt = 0;
    __syncthreads();
    const float4* p = obj4 + (size_t)img * (AHW / 4);
    int v0 = blockIdx.x * 768;
    #pragma unroll
    for (int it = 0; it < 3; ++it) {
        int v = v0 + it * 256 + threadIdx.x;
        float4 f = p[v];
        int jb = v * 4;
        #pragma unroll
        for (int k = 0; k < 4; ++k) {
            float x = k == 0 ? f.x : (k == 1 ? f.y : (k == 2 ? f.z : f.w));
            unsigned m = mapf(x);
            if (m >= thr) {
                int j = jb + k;
                int a = j >> 16;
                int hw = j & 65535;
                unsigned idx = (unsigned)(hw * A + a);
                unsigned pos = atomicAdd(&lcnt, 1u);
                if (pos < LBUF)
                    lbuf[pos] = ((unsigned long long)m << 32) | (unsigned)(~idx);
            }
        }
    }
    __syncthreads();
    unsigned n = lcnt > LBUF ? LBUF : lcnt;
    if (threadIdx.x == 0) gbase = atomicAdd(&selcnt[img * 64], n);
    __syncthreads();
    if (threadIdx.x < n) {
        unsigned pos = gbase + threadIdx.x;
        if (pos < CAP2)
            keys[(size_t)img * CAP2 + pos] = lbuf[threadIdx.x];
    }
}

// K6: per-image bitonic sort, descending. Tail beyond the valid count is
// padded with 0 keys in LDS (keys buffer itself is not zeroed).
__global__ void __launch_bounds__(1024) k_sort(unsigned long long* __restrict__ keys,
                                               const unsigned* __restrict__ selcnt) {
    __shared__ unsigned long long s[CAP2];
    int img = blockIdx.x;
    unsigned cnt = selcnt[img * 64];
    if (cnt > CAP2) cnt = CAP2;
    unsigned long long* g = keys + (size_t)img * CAP2;
    for (int i = threadIdx.x; i < CAP2; i += 1024)
        s[i] = (i < (int)cnt) ? g[i] : 0ULL;
    __syncthreads();
    for (int k2 = 2; k2 <= CAP2; k2 <<= 1) {
        for (int j = k2 >> 1; j > 0; j >>= 1) {
            for (int i = threadIdx.x; i < CAP2; i += 1024) {
                int ixj = i ^ j;
                if (ixj > i) {
                    unsigned long long a = s[i], b = s[ixj];
                    bool up = ((i & k2) == 0);
                    if (up ? (a < b) : (a > b)) { s[i] = b; s[ixj] = a; }
                }
            }
            __syncthreads();
        }
    }
    for (int i = threadIdx.x; i < PRE; i += 1024) g[i] = s[i];
}

// K7: decode boxes (f64), clip, MIN_SIZE filter, sigmoid score.
// boxesf is PADDED to MROWS with sentinel boxes (never overlap).
__global__ void k_decode(const float* __restrict__ anchors, const float* __restrict__ br,
                         const unsigned long long* __restrict__ keys,
                         double* __restrict__ boxes, float4* __restrict__ boxesf,
                         float* __restrict__ scores, unsigned* __restrict__ negmask) {
    int g = blockIdx.x * blockDim.x + threadIdx.x;
    if (g >= NIMG * MROWS) return;
    int img = g >> 11, r = g & (MROWS - 1);
    float4* bfp = boxesf + (size_t)img * MROWS + r;
    if (r >= PRE) {
        float4 bf;
        bf.x = 1e8f; bf.y = 1e8f; bf.z = -1e8f; bf.w = -1e8f;
        *bfp = bf;
        return;
    }
    unsigned long long key = keys[(size_t)img * CAP2 + r];
    unsigned m = (unsigned)(key >> 32);
    unsigned idx = ~(unsigned)key;
    unsigned u = (m & 0x80000000u) ? (m ^ 0x80000000u) : ~m;
    float x = __uint_as_float(u);
    double sc = 1.0 / (1.0 + exp(-(double)x));
    int a = idx % 3;
    int hw = idx / 3;
    const float* anc = anchors + ((size_t)img * AHW + idx) * 4;
    double ax1 = anc[0], ay1 = anc[1], ax2 = anc[2], ay2 = anc[3];
    double aw = ax2 - ax1 + 1.0, ah = ay2 - ay1 + 1.0;
    double cx = ax1 + 0.5 * aw, cy = ay1 + 0.5 * ah;
    const float* bp = br + (size_t)img * 12 * HW + (size_t)a * 4 * HW + hw;
    double dx = bp[0];
    double dy = bp[(size_t)HW];
    double dw = bp[(size_t)2 * HW];
    double dh = bp[(size_t)3 * HW];
    const double CLIPV = 4.135166556742356; // log(1000/16)
    dw = fmin(dw, CLIPV); dh = fmin(dh, CLIPV);
    double pcx = dx * aw + cx, pcy = dy * ah + cy;
    double pw = exp(dw) * aw, ph = exp(dh) * ah;
    double x1 = pcx - 0.5 * pw, y1 = pcy - 0.5 * ph;
    double x2 = pcx + 0.5 * pw - 1.0, y2 = pcy + 0.5 * ph - 1.0;
    x1 = fmin(fmax(x1, 0.0), 1023.0);
    y1 = fmin(fmax(y1, 0.0), 1023.0);
    x2 = fmin(fmax(x2, 0.0), 1023.0);
    y2 = fmin(fmax(y2, 0.0), 1023.0);
    bool keep = (x2 - x1 + 1.0 >= 0.0) && (y2 - y1 + 1.0 >= 0.0);
    double* bo = boxes + ((size_t)img * PRE + r) * 4;
    bo[0] = x1; bo[1] = y1; bo[2] = x2; bo[3] = y2;
    float4 bf;
    bf.x = (float)x1; bf.y = (float)y1; bf.z = (float)x2; bf.w = (float)y2;
    *bfp = bf;
    scores[img * PRE + r] = keep ? (float)sc : NEGF;
    if (!keep) atomicOr(&negmask[img * 64 + (r >> 5)], 1u << (r & 31));
}

// exact f64 rebuild of one mask row's parity-k words (rare path)
__device__ __noinline__ unsigned fixup_row(const double* __restrict__ base64,
                                           const float4* __restrict__ fb,
                                           int r, int t, int k0,
                                           float4 P, float Arow) {
    const double* ri = base64 + (size_t)r * 4;
    double X1 = ri[0], Y1 = ri[1], X2 = ri[2], Y2 = ri[3];
    double AR = (X2 - X1 + 1.0) * (Y2 - Y1 + 1.0);
    unsigned myw = 0;
    for (int k = k0; k < 32; k += 2) {
        int col = 64 * k + t;
        float4 q = fb[col];
        float Ac = 0.7f * ((q.z - q.x + 1.0f) * (q.w - q.y + 1.0f));
        float iw = fminf(P.z, q.z) - fmaxf(P.x, q.x) + 1.0f;
        float ih = fminf(P.w, q.w) - fmaxf(P.y, q.y) + 1.0f;
        float inter = iw * ih;
        float d = fmaf(1.7f, inter, -(Arow + Ac));
        bool ov = (iw > -BW) & (ih > -BW);
        bool need = ov & ((iw < BW) | (ih < BW) | (fabsf(d) < BD));
        bool res = ov & (d > 0.0f);
        if (need) {   // col < PRE guaranteed (sentinels can't set need)
            const double* rj = base64 + (size_t)col * 4;
            double bX1 = rj[0], bY1 = rj[1], bX2 = rj[2], bY2 = rj[3];
            double IW = fmin(X2, bX2) - fmax(X1, bX1) + 1.0;
            double IH = fmin(Y2, bY2) - fmax(Y1, bY1) + 1.0;
            IW = IW > 0.0 ? IW : 0.0;
            IH = IH > 0.0 ? IH : 0.0;
            double INTER = IW * IH;
            double AJ = (bX2 - bX1 + 1.0) * (bY2 - bY1 + 1.0);
            double IOU = INTER / ((AR + AJ) - INTER);
            res = IOU > 0.7;
        }
        unsigned long long bb = __ballot(res);
        myw = (t == 2 * k) ? (unsigned)bb : myw;
        myw = (t == 2 * k + 1) ? (unsigned)(bb >> 32) : myw;
    }
    return myw;
}

// K8: upper-triangle IoU suppression bitmask, TRANSPOSED output:
// maskT[img][word t][row r] so k_nms can load 16 consecutive rows of its
// word-lane with 4 dwordx4 loads. No LDS; boxesf L1/L2-resident.
// Each (quad-pair, k-parity) is one wave; per-lane uint4 store of its
// 4-row quad column (predicated by word ownership).
#define ROWOP(P, Arow, wreg, nflag)                                \
    {                                                              \
        float iw = fminf(P.z, Q.z) - fmaxf(P.x, Q.x) + 1.0f;       \
        float ih = fminf(P.w, Q.w) - fmaxf(P.y, Q.y) + 1.0f;       \
        float inter = iw * ih;                                     \
        float d = fmaf(1.7f, inter, -(Arow + Ac));                 \
        bool ov = (iw > -BW) & (ih > -BW);                         \
        nflag |= ov & ((iw < BW) | (ih < BW) | (fabsf(d) < BD));   \
        bool res = ov & (d > 0.0f);                                \
        unsigned long long bb = __ballot(res);                     \
        wreg = (t == 2 * k) ? (unsigned)bb : wreg;                 \
        wreg = (t == 2 * k + 1) ? (unsigned)(bb >> 32) : wreg;     \
    }

__global__ void __launch_bounds__(256) k_mask(const float4* __restrict__ boxesf,
                                              const double* __restrict__ boxes,
                                              unsigned* __restrict__ maskT) {
    int img = blockIdx.y;
    int tid = threadIdx.x;
    int wave = tid >> 6, t = tid & 63;
    int wgid = blockIdx.x * 4 + wave;       // 0..499
    int pairIdx = wgid >> 1;                // 0..249
    int khalf = wgid & 1;
    const float4* fb = boxesf + (size_t)img * MROWS;
    const double* base64 = boxes + (size_t)img * PRE * 4;
    unsigned* mtw = maskT + ((size_t)img * 64 + t) * MROWS;
    int tw = t >> 1;
    for (int half = 0; half < 2; ++half) {
        int q = (half == 0) ? pairIdx : (NQUAD - 1 - pairIdx);
        int r0 = q * 4;
        float4 P0 = fb[r0], P1 = fb[r0 + 1], P2 = fb[r0 + 2], P3 = fb[r0 + 3];
        float A0 = 0.7f * ((P0.z - P0.x + 1.0f) * (P0.w - P0.y + 1.0f));
        float A1 = 0.7f * ((P1.z - P1.x + 1.0f) * (P1.w - P1.y + 1.0f));
        float A2 = 0.7f * ((P2.z - P2.x + 1.0f) * (P2.w - P2.y + 1.0f));
        float A3 = 0.7f * ((P3.z - P3.x + 1.0f) * (P3.w - P3.y + 1.0f));
        int kmin = q >> 4;
        int k0 = kmin + ((khalf ^ (kmin & 1)) & 1);   // first k with (k&1)==khalf
        unsigned w0 = 0, w1 = 0, w2 = 0, w3 = 0;
        bool n0 = false, n1 = false, n2 = false, n3 = false;
        for (int k = k0; k < 32; k += 2) {
            int col = 64 * k + t;
            float4 Q = fb[col];
            float Ac = 0.7f * ((Q.z - Q.x + 1.0f) * (Q.w - Q.y + 1.0f));
            ROWOP(P0, A0, w0, n0)
            ROWOP(P1, A1, w1, n1)
            ROWOP(P2, A2, w2, n2)
            ROWOP(P3, A3, w3, n3)
        }
        if (__any(n0)) w0 = fixup_row(base64, fb, r0 + 0, t, k0, P0, A0);
        if (__any(n1)) w1 = fixup_row(base64, fb, r0 + 1, t, k0, P1, A1);
        if (__any(n2)) w2 = fixup_row(base64, fb, r0 + 2, t, k0, P2, A2);
        if (__any(n3)) w3 = fixup_row(base64, fb, r0 + 3, t, k0, P3, A3);
        bool own = (tw >= kmin) && ((tw & 1) == khalf);
        if (own) {
            uint4 v;
            v.x = w0; v.y = w1; v.z = w2; v.w = w3;
            *(uint4*)(mtw + r0) = v;    // r0 % 4 == 0 -> 16B aligned
        }
    }
}

// K9: sequential-scan greedy NMS. Transposed mask: lane t loads word t of 16
// consecutive rows with 4 dwordx4 loads -> 8-deep group pipeline fits vmcnt
// (32 outstanding <= 63); load->use distance ~7 bodies covers HBM latency.
// sched_barrier(0) pins each load block's issue slot.
#define NMS_LOAD(B, G) {                                        \
    B[0] = *(const uint4*)(mt + (G) * 16 + 0);                  \
    B[1] = *(const uint4*)(mt + (G) * 16 + 4);                  \
    B[2] = *(const uint4*)(mt + (G) * 16 + 8);                  \
    B[3] = *(const uint4*)(mt + (G) * 16 + 12); }

#define NMS_ONE(BV, S, PAR, W) {                                \
    unsigned rb = (unsigned)__builtin_amdgcn_readlane((int)(BV), W); \
    unsigned sh = ((PAR) << 4) + (S);                           \
    unsigned bit = (s_cur >> sh) & 1u;                          \
    unsigned am = bit - 1u;  /* alive: ~0, dead: 0 */           \
    s_cur |= rb & am;                                           \
    s_pick |= am & (1u << sh);                                  \
    sup |= (BV) & am; }

#define NMS_PROC(B, G, PAR) {                                   \
    int W = (G) >> 1;                                           \
    if ((PAR) == 0) s_cur = (unsigned)__builtin_amdgcn_readlane((int)sup, W); \
    NMS_ONE(B[0].x, 0, PAR, W) NMS_ONE(B[0].y, 1, PAR, W)       \
    NMS_ONE(B[0].z, 2, PAR, W) NMS_ONE(B[0].w, 3, PAR, W)       \
    NMS_ONE(B[1].x, 4, PAR, W) NMS_ONE(B[1].y, 5, PAR, W)       \
    NMS_ONE(B[1].z, 6, PAR, W) NMS_ONE(B[1].w, 7, PAR, W)       \
    NMS_ONE(B[2].x, 8, PAR, W) NMS_ONE(B[2].y, 9, PAR, W)       \
    NMS_ONE(B[2].z, 10, PAR, W) NMS_ONE(B[2].w, 11, PAR, W)     \
    NMS_ONE(B[3].x, 12, PAR, W) NMS_ONE(B[3].y, 13, PAR, W)     \
    NMS_ONE(B[3].z, 14, PAR, W) NMS_ONE(B[3].w, 15, PAR, W)     \
    if ((PAR) == 1) {                                           \
        pickedv = (t == W) ? (int)s_pick : pickedv;             \
        np += __builtin_popcount(s_pick);                       \
        s_pick = 0;                                             \
    }                                                           \
}

__global__ void __launch_bounds__(64) k_nms(const double* __restrict__ boxes,
                                            const float* __restrict__ scores,
                                            const unsigned* __restrict__ negmask,
                                            const unsigned* __restrict__ maskT,
                                            float* __restrict__ out) {
    __shared__ int picks[POST];
    __shared__ unsigned wcnt[64];
    __shared__ int tot;
    int img = blockIdx.x;
    int t = threadIdx.x;
    unsigned sup = negmask[img * 64 + t];
    if (t == 62) sup |= 0xFFFF0000u;  // indices 2000..2015 invalid
    if (t == 63) sup = 0xFFFFFFFFu;   // indices 2016..2047 invalid
    const unsigned* mt = maskT + ((size_t)img * 64 + t) * MROWS;
    uint4 b0[4], b1[4], b2[4], b3[4], b4[4], b5[4], b6[4], b7[4];
    NMS_LOAD(b0, 0) NMS_LOAD(b1, 1) NMS_LOAD(b2, 2) NMS_LOAD(b3, 3)
    NMS_LOAD(b4, 4) NMS_LOAD(b5, 5) NMS_LOAD(b6, 6) NMS_LOAD(b7, 7)
    __builtin_amdgcn_sched_barrier(0);
    int np = 0;
    unsigned s_cur = 0, s_pick = 0;
    int pickedv = 0;
    // 125 groups of 16 rows. Main: groups 0..119 (8-deep); epilogue 120..124.
    for (int gg = 0; gg < 120; gg += 8) {
        NMS_PROC(b0, gg + 0, 0) NMS_LOAD(b0, gg + 8)  __builtin_amdgcn_sched_barrier(0);
        NMS_PROC(b1, gg + 1, 1) NMS_LOAD(b1, gg + 9)  __builtin_amdgcn_sched_barrier(0);
        NMS_PROC(b2, gg + 2, 0) NMS_LOAD(b2, gg + 10) __builtin_amdgcn_sched_barrier(0);
        NMS_PROC(b3, gg + 3, 1) NMS_LOAD(b3, gg + 11) __builtin_amdgcn_sched_barrier(0);
        NMS_PROC(b4, gg + 4, 0) NMS_LOAD(b4, gg + 12) __builtin_amdgcn_sched_barrier(0);
        NMS_PROC(b5, gg + 5, 1) NMS_LOAD(b5, gg + 13) __builtin_amdgcn_sched_barrier(0);
        NMS_PROC(b6, gg + 6, 0) NMS_LOAD(b6, gg + 14) __builtin_amdgcn_sched_barrier(0);
        NMS_PROC(b7, gg + 7, 1) NMS_LOAD(b7, gg + 15) __builtin_amdgcn_sched_barrier(0);
        if (np >= POST) break;   // 4-word aligned: s_pick == 0 here
    }
    if (np < POST) {
        NMS_PROC(b0, 120, 0) NMS_PROC(b1, 121, 1)
        NMS_PROC(b2, 122, 0) NMS_PROC(b3, 123, 1)
        NMS_PROC(b4, 124, 0)   // rows 1984..1999, word 62 low half
        pickedv = (t == 62) ? (int)s_pick : pickedv;
        np += __builtin_popcount(s_pick);
    }
    // epilogue: materialize picks[] from the bitmap (lane W holds word W)
    wcnt[t] = (unsigned)__builtin_popcount((unsigned)pickedv);
    __syncthreads();
    int pre = 0;
    for (int i = 0; i < t; ++i) pre += (int)wcnt[i];
    if (t == 63) tot = pre + (int)wcnt[63];
    __syncthreads();
    unsigned pw = (unsigned)pickedv;
    int rank = pre;
    while (pw) {
        int b = __ffs(pw) - 1;
        pw &= pw - 1;
        if (rank < POST) picks[rank] = t * 32 + b;
        rank++;
    }
    __syncthreads();
    int np_final = tot > POST ? POST : tot;
    float* ob = out + (size_t)img * POST * 4;
    float* os = out + (size_t)NIMG * POST * 4 + (size_t)img * POST;
    for (int k = t; k < POST; k += 64) {
        if (k < np_final) {
            int p = picks[k];
            const double* bp = boxes + ((size_t)img * PRE + p) * 4;
            ob[k * 4 + 0] = (float)bp[0];
            ob[k * 4 + 1] = (float)bp[1];
            ob[k * 4 + 2] = (float)bp[2];
            ob[k * 4 + 3] = (float)bp[3];
            os[k] = scores[img * PRE + p];
        } else {
            ob[k * 4 + 0] = 0.0f; ob[k * 4 + 1] = 0.0f;
            ob[k * 4 + 2] = 0.0f; ob[k * 4 + 3] = 0.0f;
            os[k] = NEGF;
        }
    }
}

extern "C" void kernel_launch(void* const* d_in, const int* in_sizes, int n_in,
                              void* d_out, int out_size, void* d_ws, size_t ws_size,
                              hipStream_t stream) {
    const float* anchors = (const float*)d_in[0];
    const float4* obj4 = (const float4*)d_in[1];
    const float* br = (const float*)d_in[2];
    float* out = (float*)d_out;

    char* ws = (char*)d_ws;
    size_t off = 0;
    auto alloc = [&](size_t bytes) {
        void* p = ws + off;
        off = (off + bytes + 255) & ~(size_t)255;
        return p;
    };
    // zero-initialized region (single fused memset): hist..negmask
    unsigned* hist = (unsigned*)alloc((size_t)NIMG * NBUCKET * 4);
    unsigned* hist2 = (unsigned*)alloc((size_t)NIMG * NBUCKET * 4);
    unsigned* bsel = (unsigned*)alloc(NIMG * 4);
    unsigned* cntAbove = (unsigned*)alloc(NIMG * 4);
    unsigned* thr32 = (unsigned*)alloc(NIMG * 4);
    unsigned* selcnt = (unsigned*)alloc((size_t)NIMG * 64 * 4);      // one cache line per image
    unsigned* negmask = (unsigned*)alloc((size_t)NIMG * 64 * 4);
    size_t zero_bytes = off;
    // non-zeroed buffers
    unsigned long long* keys = (unsigned long long*)alloc((size_t)NIMG * CAP2 * 8);
    double* boxes = (double*)alloc((size_t)NIMG * PRE * 4 * 8);
    float4* boxesf = (float4*)alloc((size_t)NIMG * MROWS * 16);
    float* scores = (float*)alloc((size_t)NIMG * PRE * 4);
    unsigned* maskT = (unsigned*)alloc((size_t)NIMG * 64 * MROWS * 4);

    hipMemsetAsync(hist, 0, zero_bytes, stream);

    k_hist<<<dim3(64, NIMG), 256, 0, stream>>>(obj4, hist);
    k_thresh<<<NIMG, 256, 0, stream>>>(hist, bsel, cntAbove);
    k_hist2<<<dim3(64, NIMG), 256, 0, stream>>>(obj4, bsel, hist2);
    k_thresh2<<<NIMG, 256, 0, stream>>>(hist2, bsel, cntAbove, thr32);
    k_compact<<<dim3(64, NIMG), 256, 0, stream>>>(obj4, thr32, selcnt, keys);
    k_sort<<<NIMG, 1024, 0, stream>>>(keys, selcnt);
    k_decode<<<(NIMG * MROWS + 255) / 256, 256, 0, stream>>>(anchors, br, keys, boxes, boxesf, scores, negmask);
    k_mask<<<dim3(125, NIMG), 256, 0, stream>>>(boxesf, boxes, maskT);
    k_nms<<<NIMG, 64, 0, stream>>>(boxes, scores, negmask, maskT, out);
}